// Round 1
// baseline (1623.229 us; speedup 1.0000x reference)
//
#include <hip/hip_runtime.h>
#include <math.h>

// ============================================================================
// RPN pipeline for MI355X.
// Levels: L0: H=W=32, stride 8, scale 4096 ; L1: H=W=16, stride 16, scale 16384
// A=3 ratios {0.5, 1, 2}. N0 = 3072, N1 = 768 anchors per batch. BS = 4.
// Score path accumulated in fp64 to preserve the reference's sort order
// (output is a permutation-gather; a single rank flip costs absmax ~256).
// ============================================================================

// ---------------- transpose conv_w [256][2304] -> w_t [2304][256] -----------
__global__ void transpose_w_k(const float* __restrict__ w, float* __restrict__ wt) {
  int idx = blockIdx.x * 256 + threadIdx.x;           // over 2304*256
  if (idx >= 2304 * 256) return;
  int k = idx >> 8, oc = idx & 255;
  wt[idx] = w[oc * 2304 + k];
}

// ---------------- conv3x3 + bias + ReLU as implicit GEMM (fp64 acc) ---------
// out[p][oc] = relu( sum_k w_t[k][oc] * im2col(k,p) + b[oc] ),  K = 2304
// 64x64 tile, 256 threads, thread computes oc in {ty+16i}, px in {tx+16j}
template <int H, int W>
__global__ __launch_bounds__(256) void conv3_gemm(
    const float* __restrict__ feat,   // [4][256][H][W]
    const float* __restrict__ wt,     // [2304][256]
    const float* __restrict__ bias,   // [256]
    float* __restrict__ xt)           // [4*H*W][256]
{
  constexpr int HW = H * W;
  __shared__ double Ald[16][64];
  __shared__ double Bld[16][64];
  const int t = threadIdx.x;
  const int tx = t & 15, ty = t >> 4;
  const int oc_base = blockIdx.x * 64;
  const int p_base  = blockIdx.y * 64;
  double acc[4][4] = {};
  for (int k0 = 0; k0 < 2304; k0 += 16) {
#pragma unroll
    for (int r = 0; r < 4; ++r) {                     // stage A (weights)
      int e = t + r * 256;
      int kk = e >> 6, ocl = e & 63;
      Ald[kk][ocl] = (double)wt[(k0 + kk) * 256 + oc_base + ocl];
    }
#pragma unroll
    for (int r = 0; r < 4; ++r) {                     // stage B (im2col)
      int e = t + r * 256;
      int kk = e >> 6, pxl = e & 63;
      int p = p_base + pxl;
      int b = p / HW, pin = p % HW;
      int y = pin / W, x = pin % W;
      int k = k0 + kk;
      int ic = k / 9, rr = k - ic * 9;
      int ky = rr / 3, kx = rr - ky * 3;
      int iy = y + ky - 1, ix = x + kx - 1;
      float v = 0.f;
      if ((unsigned)iy < (unsigned)H && (unsigned)ix < (unsigned)W)
        v = feat[((b * 256 + ic) * H + iy) * W + ix];
      Bld[kk][pxl] = (double)v;
    }
    __syncthreads();
#pragma unroll
    for (int kk = 0; kk < 16; ++kk) {
      double a[4], bb[4];
#pragma unroll
      for (int i = 0; i < 4; ++i) a[i] = Ald[kk][ty + 16 * i];
#pragma unroll
      for (int j = 0; j < 4; ++j) bb[j] = Bld[kk][tx + 16 * j];
#pragma unroll
      for (int i = 0; i < 4; ++i)
#pragma unroll
        for (int j = 0; j < 4; ++j) acc[i][j] += a[i] * bb[j];
    }
    __syncthreads();
  }
#pragma unroll
  for (int i = 0; i < 4; ++i) {
    int oc = oc_base + ty + 16 * i;
    double bv = (double)bias[oc];
#pragma unroll
    for (int j = 0; j < 4; ++j) {
      int p = p_base + tx + 16 * j;
      float f = (float)(acc[i][j] + bv);
      xt[(size_t)p * 256 + oc] = f > 0.f ? f : 0.f;
    }
  }
}

// 64x16 tile variant (level 1: more blocks for occupancy)
template <int H, int W>
__global__ __launch_bounds__(256) void conv3_gemm_n16(
    const float* __restrict__ feat, const float* __restrict__ wt,
    const float* __restrict__ bias, float* __restrict__ xt)
{
  constexpr int HW = H * W;
  __shared__ double Ald[16][64];
  __shared__ double Bld[16][16];
  const int t = threadIdx.x;
  const int tx = t & 15, ty = t >> 4;
  const int oc_base = blockIdx.x * 64;
  const int p_base  = blockIdx.y * 16;
  double acc[4] = {};
  for (int k0 = 0; k0 < 2304; k0 += 16) {
#pragma unroll
    for (int r = 0; r < 4; ++r) {
      int e = t + r * 256;
      int kk = e >> 6, ocl = e & 63;
      Ald[kk][ocl] = (double)wt[(k0 + kk) * 256 + oc_base + ocl];
    }
    {
      int kk = t >> 4, pxl = t & 15;
      int p = p_base + pxl;
      int b = p / HW, pin = p % HW;
      int y = pin / W, x = pin % W;
      int k = k0 + kk;
      int ic = k / 9, rr = k - ic * 9;
      int ky = rr / 3, kx = rr - ky * 3;
      int iy = y + ky - 1, ix = x + kx - 1;
      float v = 0.f;
      if ((unsigned)iy < (unsigned)H && (unsigned)ix < (unsigned)W)
        v = feat[((b * 256 + ic) * H + iy) * W + ix];
      Bld[kk][pxl] = (double)v;
    }
    __syncthreads();
#pragma unroll
    for (int kk = 0; kk < 16; ++kk) {
      double bb = Bld[kk][tx];
#pragma unroll
      for (int i = 0; i < 4; ++i) acc[i] += Ald[kk][ty + 16 * i] * bb;
    }
    __syncthreads();
  }
#pragma unroll
  for (int i = 0; i < 4; ++i) {
    int oc = oc_base + ty + 16 * i;
    float f = (float)(acc[i] + (double)bias[oc]);
    xt[(size_t)(p_base + tx) * 256 + oc] = f > 0.f ? f : 0.f;
  }
}

// ---------------- 1x1 heads (cls 3ch, reg 12ch), fp64 acc -------------------
__global__ __launch_bounds__(256) void heads_k(
    const float* __restrict__ x0t, const float* __restrict__ x1t,
    const float* __restrict__ cls_w, const float* __restrict__ cls_b,
    const float* __restrict__ reg_w, const float* __restrict__ reg_b,
    float* __restrict__ cls0, float* __restrict__ reg0,
    float* __restrict__ cls1, float* __restrict__ reg1)
{
  int tid = blockIdx.x * 256 + threadIdx.x;
  int pid = tid >> 4;
  int o = tid & 15;
  if (o == 15 || pid >= 5120) return;
  const float* xr;
  int b, pin, lvl;
  if (pid < 4096) { lvl = 0; xr = x0t + (size_t)pid * 256; b = pid >> 10; pin = pid & 1023; }
  else { int p1 = pid - 4096; lvl = 1; xr = x1t + (size_t)p1 * 256; b = p1 >> 8; pin = p1 & 255; }
  const float* wr; float bv;
  if (o < 3) { wr = cls_w + o * 256; bv = cls_b[o]; }
  else { int e = o - 3; wr = reg_w + e * 256; bv = reg_b[e]; }
  double acc = 0.0;
  const float4* x4 = (const float4*)xr;
  const float4* w4 = (const float4*)wr;
#pragma unroll 4
  for (int c = 0; c < 64; ++c) {
    float4 xv = x4[c], wv = w4[c];
    acc += (double)xv.x * (double)wv.x + (double)xv.y * (double)wv.y +
           (double)xv.z * (double)wv.z + (double)xv.w * (double)wv.w;
  }
  float out = (float)(acc + (double)bv);
  if (o < 3) {
    if (lvl == 0) cls0[b * 3072 + pin * 3 + o] = out;
    else          cls1[b * 768 + pin * 3 + o] = out;
  } else {
    int e = o - 3, a = e >> 2, d = e & 3;
    if (lvl == 0) reg0[((size_t)b * 3072 + pin * 3 + a) * 4 + d] = out;
    else          reg1[((size_t)b * 768 + pin * 3 + a) * 4 + d] = out;
  }
}

// ---------------- anchor gen + box decode + clamp + sigmoid -----------------
__global__ void decode_k(
    const float* __restrict__ cls0, const float* __restrict__ reg0,
    const float* __restrict__ cls1, const float* __restrict__ reg1,
    float* __restrict__ box0, float* __restrict__ sc0,
    float* __restrict__ box1, float* __restrict__ sc1)
{
  int id = blockIdx.x * 256 + threadIdx.x;
  if (id >= 4 * 3840) return;
  int b = id / 3840, m = id - b * 3840;
  int lvl = (m >= 3072) ? 1 : 0;
  int n = lvl ? (m - 3072) : m;
  int Wd = lvl ? 16 : 32;
  float S = lvl ? 16.f : 8.f;
  double scale = lvl ? 16384.0 : 4096.0;
  int pin = n / 3, a = n - pin * 3;
  int y = pin / Wd, x = pin - y * Wd;
  double ratio = (a == 0) ? 0.5 : (a == 1 ? 1.0 : 2.0);
  float w_a = (float)sqrt(scale / ratio);   // matches np: fp64 sqrt -> fp32
  float h_a = (float)sqrt(scale * ratio);
  float cx = ((float)x + 0.5f) * S;
  float cy = ((float)y + 0.5f) * S;
  float x1 = cx - 0.5f * w_a, y1 = cy - 0.5f * h_a;
  float x2 = cx + 0.5f * w_a, y2 = cy + 0.5f * h_a;
  x1 = fminf(fmaxf(x1, 0.f), 256.f); y1 = fminf(fmaxf(y1, 0.f), 256.f);
  x2 = fminf(fmaxf(x2, 0.f), 256.f); y2 = fminf(fmaxf(y2, 0.f), 256.f);
  float wa = x2 - x1, ha = y2 - y1;
  float cxa = x1 + 0.5f * wa, cya = y1 + 0.5f * ha;
  const float* rg = lvl ? &reg1[((size_t)b * 768 + n) * 4] : &reg0[((size_t)b * 3072 + n) * 4];
  float dx = rg[0], dy = rg[1], dw = rg[2], dh = rg[3];
  float ncx = dx * wa + cxa;
  float ncy = dy * ha + cya;
  float nw = expf(dw) * wa;
  float nh = expf(dh) * ha;
  float bx1 = ncx - 0.5f * nw, by1 = ncy - 0.5f * nh;
  float bx2 = ncx + 0.5f * nw, by2 = ncy + 0.5f * nh;
  bx1 = fminf(fmaxf(bx1, 0.f), 256.f); by1 = fminf(fmaxf(by1, 0.f), 256.f);
  bx2 = fminf(fmaxf(bx2, 0.f), 256.f); by2 = fminf(fmaxf(by2, 0.f), 256.f);
  float c = lvl ? cls1[b * 768 + n] : cls0[b * 3072 + n];
  float s = 1.f / (1.f + expf(-c));
  float* bo = lvl ? &box1[((size_t)b * 768 + n) * 4] : &box0[((size_t)b * 3072 + n) * 4];
  bo[0] = bx1; bo[1] = by1; bo[2] = bx2; bo[3] = by2;
  if (lvl) sc1[b * 768 + n] = s; else sc0[b * 3072 + n] = s;
}

// ---------------- stable descending enumeration sort per (batch,level) ------
__global__ __launch_bounds__(256) void sort_level_k(
    const float* __restrict__ sc, const float* __restrict__ box,
    float* __restrict__ ssc, float* __restrict__ sbox, int N, int nblk)
{
  __shared__ float s[3072];
  int b = blockIdx.x / nblk;
  int c = blockIdx.x - b * nblk;
  const float* scb = sc + (size_t)b * N;
  for (int j = threadIdx.x; j < N; j += 256) s[j] = scb[j];
  __syncthreads();
  int i = c * 256 + threadIdx.x;
  float si = s[i];
  int rank = 0;
  for (int j = 0; j < N; ++j) {
    float sj = s[j];
    rank += (sj > si) || (sj == si && j < i);
  }
  ssc[(size_t)b * N + rank] = si;
  float4 bi = ((const float4*)box)[(size_t)b * N + i];
  ((float4*)sbox)[(size_t)b * N + rank] = bi;
}

// ---------------- NMS suppression bitmask: bit j of mask[b][i][w] -----------
__global__ void nms_mask_k(const float* __restrict__ sbox,
                           unsigned long long* __restrict__ mask,
                           int N, int words)
{
  int idx = blockIdx.x * 256 + threadIdx.x;
  if (idx >= 4 * N * words) return;
  int w = idx % words;
  int tmp = idx / words;
  int i = tmp % N;
  int b = tmp / N;
  float4 bi = ((const float4*)sbox)[(size_t)b * N + i];
  float ai = (bi.z - bi.x) * (bi.w - bi.y);
  unsigned long long m = 0ull;
  const float4* bj4 = ((const float4*)sbox) + (size_t)b * N + (size_t)w * 64;
#pragma unroll 8
  for (int jj = 0; jj < 64; ++jj) {
    int j = w * 64 + jj;
    float4 bj = bj4[jj];
    float lx = fmaxf(bi.x, bj.x), ly = fmaxf(bi.y, bj.y);
    float rx = fminf(bi.z, bj.z), ry = fminf(bi.w, bj.w);
    float iw = fmaxf(rx - lx, 0.f), ih = fmaxf(ry - ly, 0.f);
    float inter = iw * ih;
    float aj = (bj.z - bj.x) * (bj.w - bj.y);
    float iou = inter / (ai + aj - inter);   // NaN (0/0) compares false, matches jnp
    if (iou > 0.7f && j > i) m |= (1ull << jj);
  }
  mask[idx] = m;   // idx == (b*N + i)*words + w
}

// ---------------- exact greedy scan, one wave per (batch,level) -------------
__global__ __launch_bounds__(64) void nms_scan_k(
    const float* __restrict__ ssc0, const float* __restrict__ sbox0,
    const unsigned long long* __restrict__ mask0,
    const float* __restrict__ ssc1, const float* __restrict__ sbox1,
    const unsigned long long* __restrict__ mask1,
    float* __restrict__ cb, float* __restrict__ cs)
{
  __shared__ unsigned long long diag[64];
  int z = blockIdx.x;
  int lvl = z >> 2, b = z & 3;
  int N = lvl ? 768 : 3072;
  int words = lvl ? 12 : 48;
  const float* ssc = lvl ? ssc1 : ssc0;
  const float* sbox = lvl ? sbox1 : sbox0;
  const unsigned long long* mask = (lvl ? mask1 : mask0) + (size_t)b * N * words;
  const int lane = threadIdx.x;
  float* cbb = cb + ((size_t)b * 2000 + lvl * 1000) * 4;
  float* csb = cs + (size_t)b * 2000 + lvl * 1000;
  for (int q = lane; q < 1000; q += 64) {           // -1 padding init
    csb[q] = -1.f;
    ((float4*)cbb)[q] = make_float4(-1.f, -1.f, -1.f, -1.f);
  }
  __syncthreads();
  unsigned long long removed = 0ull;
  int kept_base = 0;
  for (int t = 0; t < words; ++t) {
    unsigned long long wr = __shfl(removed, t);     // removed word for this tile
    int i = t * 64 + lane;
    diag[lane] = mask[(size_t)i * words + t];
    __syncthreads();
    unsigned long long r = wr, keep64 = 0ull;
#pragma unroll
    for (int bb = 0; bb < 64; ++bb) {               // serial greedy inside tile
      unsigned long long m = diag[bb];
      if (((r >> bb) & 1ull) == 0ull) { keep64 |= (1ull << bb); r |= m; }
    }
    __syncthreads();
    if ((keep64 >> lane) & 1ull) {                  // emit kept
      int rank = kept_base + __popcll(keep64 & ((1ull << lane) - 1ull));
      if (rank < 1000) {
        csb[rank] = ssc[(size_t)b * N + i];
        ((float4*)cbb)[rank] = ((const float4*)sbox)[(size_t)b * N + i];
      }
    }
    if (lane > t && lane < words) {                 // propagate suppression
      unsigned long long acc = removed;
      const unsigned long long* row = mask + (size_t)t * 64 * words + lane;
#pragma unroll 16
      for (int bb = 0; bb < 64; ++bb) {
        unsigned long long m = row[(size_t)bb * words];
        acc |= (((keep64 >> bb) & 1ull) ? m : 0ull);
      }
      removed = acc;
    }
    kept_base += __popcll(keep64);
  }
}

// ---------------- final stable descending sort of 2000, gather boxes --------
__global__ __launch_bounds__(256) void final_sort_k(
    const float* __restrict__ cs, const float* __restrict__ cb,
    float* __restrict__ out)
{
  __shared__ float s[2000];
  int b = blockIdx.x >> 3, c = blockIdx.x & 7;
  const float* csb = cs + (size_t)b * 2000;
  for (int j = threadIdx.x; j < 2000; j += 256) s[j] = csb[j];
  __syncthreads();
  if (threadIdx.x >= 250) return;
  int li = c * 250 + threadIdx.x;
  float si = s[li];
  int rank = 0;
  for (int j = 0; j < 2000; ++j) {
    float sj = s[j];
    rank += (sj > si) || (sj == si && j < li);
  }
  float4 bi = ((const float4*)cb)[(size_t)b * 2000 + li];
  ((float4*)out)[(size_t)b * 2000 + rank] = bi;
}

// ============================================================================
extern "C" void kernel_launch(void* const* d_in, const int* in_sizes, int n_in,
                              void* d_out, int out_size, void* d_ws, size_t ws_size,
                              hipStream_t stream) {
  const float* feat0  = (const float*)d_in[0];
  const float* feat1  = (const float*)d_in[1];
  const float* conv_w = (const float*)d_in[2];
  const float* conv_b = (const float*)d_in[3];
  const float* cls_w  = (const float*)d_in[4];
  const float* cls_b  = (const float*)d_in[5];
  const float* reg_w  = (const float*)d_in[6];
  const float* reg_b  = (const float*)d_in[7];

  char* p = (char*)d_ws;
  auto alloc = [&](size_t bytes) {
    char* r = p;
    p += (bytes + 255) & ~(size_t)255;
    return r;
  };
  float* w_t  = (float*)alloc((size_t)2304 * 256 * 4);
  float* x0t  = (float*)alloc((size_t)4096 * 256 * 4);
  float* x1t  = (float*)alloc((size_t)1024 * 256 * 4);
  float* cls0 = (float*)alloc((size_t)4 * 3072 * 4);
  float* reg0 = (float*)alloc((size_t)4 * 3072 * 16);
  float* cls1 = (float*)alloc((size_t)4 * 768 * 4);
  float* reg1 = (float*)alloc((size_t)4 * 768 * 16);
  float* box0 = (float*)alloc((size_t)4 * 3072 * 16);
  float* sc0  = (float*)alloc((size_t)4 * 3072 * 4);
  float* box1 = (float*)alloc((size_t)4 * 768 * 16);
  float* sc1  = (float*)alloc((size_t)4 * 768 * 4);
  float* sbox0 = (float*)alloc((size_t)4 * 3072 * 16);
  float* ssc0  = (float*)alloc((size_t)4 * 3072 * 4);
  float* sbox1 = (float*)alloc((size_t)4 * 768 * 16);
  float* ssc1  = (float*)alloc((size_t)4 * 768 * 4);
  unsigned long long* mask0 = (unsigned long long*)alloc((size_t)4 * 3072 * 48 * 8);
  unsigned long long* mask1 = (unsigned long long*)alloc((size_t)4 * 768 * 12 * 8);
  float* cb = (float*)alloc((size_t)4 * 2000 * 16);
  float* cs = (float*)alloc((size_t)4 * 2000 * 4);

  transpose_w_k<<<(2304 * 256 + 255) / 256, 256, 0, stream>>>(conv_w, w_t);
  conv3_gemm<32, 32><<<dim3(4, 64), 256, 0, stream>>>(feat0, w_t, conv_b, x0t);
  conv3_gemm_n16<16, 16><<<dim3(4, 64), 256, 0, stream>>>(feat1, w_t, conv_b, x1t);
  heads_k<<<320, 256, 0, stream>>>(x0t, x1t, cls_w, cls_b, reg_w, reg_b,
                                   cls0, reg0, cls1, reg1);
  decode_k<<<(4 * 3840 + 255) / 256, 256, 0, stream>>>(cls0, reg0, cls1, reg1,
                                                       box0, sc0, box1, sc1);
  sort_level_k<<<4 * 12, 256, 0, stream>>>(sc0, box0, ssc0, sbox0, 3072, 12);
  sort_level_k<<<4 * 3, 256, 0, stream>>>(sc1, box1, ssc1, sbox1, 768, 3);
  nms_mask_k<<<(4 * 3072 * 48 + 255) / 256, 256, 0, stream>>>(sbox0, mask0, 3072, 48);
  nms_mask_k<<<(4 * 768 * 12 + 255) / 256, 256, 0, stream>>>(sbox1, mask1, 768, 12);
  nms_scan_k<<<8, 64, 0, stream>>>(ssc0, sbox0, mask0, ssc1, sbox1, mask1, cb, cs);
  final_sort_k<<<32, 256, 0, stream>>>(cs, cb, (float*)d_out);
}

// Round 2
// 1072.907 us; speedup vs baseline: 1.5129x; 1.5129x over previous
//
#include <hip/hip_runtime.h>
#include <math.h>

// ============================================================================
// RPN pipeline for MI355X.
// L0: H=W=32, stride 8, scale 4096 ; L1: H=W=16, stride 16, scale 16384
// A=3 ratios {0.5,1,2}. N0=3072, N1=768 anchors/batch. BS=4.
// Score path in fp64 (R1: bitwise match vs np reference, absmax 0.0).
// R2: nms_scan rewritten — ballot-based in-register greedy (no LDS/global on
// the serial chain); col_diag_k pre-transposes diagonal tiles; nms_mask_k
// LDS-stages the 64-box tile.
// ============================================================================

__global__ void transpose_w_k(const float* __restrict__ w, float* __restrict__ wt) {
  int idx = blockIdx.x * 256 + threadIdx.x;
  if (idx >= 2304 * 256) return;
  int k = idx >> 8, oc = idx & 255;
  wt[idx] = w[oc * 2304 + k];
}

// ---------------- conv3x3 + bias + ReLU as implicit GEMM (fp64 acc) ---------
template <int H, int W>
__global__ __launch_bounds__(256) void conv3_gemm(
    const float* __restrict__ feat, const float* __restrict__ wt,
    const float* __restrict__ bias, float* __restrict__ xt)
{
  constexpr int HW = H * W;
  __shared__ double Ald[16][64];
  __shared__ double Bld[16][64];
  const int t = threadIdx.x;
  const int tx = t & 15, ty = t >> 4;
  const int oc_base = blockIdx.x * 64;
  const int p_base  = blockIdx.y * 64;
  double acc[4][4] = {};
  for (int k0 = 0; k0 < 2304; k0 += 16) {
#pragma unroll
    for (int r = 0; r < 4; ++r) {
      int e = t + r * 256;
      int kk = e >> 6, ocl = e & 63;
      Ald[kk][ocl] = (double)wt[(k0 + kk) * 256 + oc_base + ocl];
    }
#pragma unroll
    for (int r = 0; r < 4; ++r) {
      int e = t + r * 256;
      int kk = e >> 6, pxl = e & 63;
      int p = p_base + pxl;
      int b = p / HW, pin = p % HW;
      int y = pin / W, x = pin % W;
      int k = k0 + kk;
      int ic = k / 9, rr = k - ic * 9;
      int ky = rr / 3, kx = rr - ky * 3;
      int iy = y + ky - 1, ix = x + kx - 1;
      float v = 0.f;
      if ((unsigned)iy < (unsigned)H && (unsigned)ix < (unsigned)W)
        v = feat[((b * 256 + ic) * H + iy) * W + ix];
      Bld[kk][pxl] = (double)v;
    }
    __syncthreads();
#pragma unroll
    for (int kk = 0; kk < 16; ++kk) {
      double a[4], bb[4];
#pragma unroll
      for (int i = 0; i < 4; ++i) a[i] = Ald[kk][ty + 16 * i];
#pragma unroll
      for (int j = 0; j < 4; ++j) bb[j] = Bld[kk][tx + 16 * j];
#pragma unroll
      for (int i = 0; i < 4; ++i)
#pragma unroll
        for (int j = 0; j < 4; ++j) acc[i][j] += a[i] * bb[j];
    }
    __syncthreads();
  }
#pragma unroll
  for (int i = 0; i < 4; ++i) {
    int oc = oc_base + ty + 16 * i;
    double bv = (double)bias[oc];
#pragma unroll
    for (int j = 0; j < 4; ++j) {
      int p = p_base + tx + 16 * j;
      float f = (float)(acc[i][j] + bv);
      xt[(size_t)p * 256 + oc] = f > 0.f ? f : 0.f;
    }
  }
}

template <int H, int W>
__global__ __launch_bounds__(256) void conv3_gemm_n16(
    const float* __restrict__ feat, const float* __restrict__ wt,
    const float* __restrict__ bias, float* __restrict__ xt)
{
  constexpr int HW = H * W;
  __shared__ double Ald[16][64];
  __shared__ double Bld[16][16];
  const int t = threadIdx.x;
  const int tx = t & 15, ty = t >> 4;
  const int oc_base = blockIdx.x * 64;
  const int p_base  = blockIdx.y * 16;
  double acc[4] = {};
  for (int k0 = 0; k0 < 2304; k0 += 16) {
#pragma unroll
    for (int r = 0; r < 4; ++r) {
      int e = t + r * 256;
      int kk = e >> 6, ocl = e & 63;
      Ald[kk][ocl] = (double)wt[(k0 + kk) * 256 + oc_base + ocl];
    }
    {
      int kk = t >> 4, pxl = t & 15;
      int p = p_base + pxl;
      int b = p / HW, pin = p % HW;
      int y = pin / W, x = pin % W;
      int k = k0 + kk;
      int ic = k / 9, rr = k - ic * 9;
      int ky = rr / 3, kx = rr - ky * 3;
      int iy = y + ky - 1, ix = x + kx - 1;
      float v = 0.f;
      if ((unsigned)iy < (unsigned)H && (unsigned)ix < (unsigned)W)
        v = feat[((b * 256 + ic) * H + iy) * W + ix];
      Bld[kk][pxl] = (double)v;
    }
    __syncthreads();
#pragma unroll
    for (int kk = 0; kk < 16; ++kk) {
      double bb = Bld[kk][tx];
#pragma unroll
      for (int i = 0; i < 4; ++i) acc[i] += Ald[kk][ty + 16 * i] * bb;
    }
    __syncthreads();
  }
#pragma unroll
  for (int i = 0; i < 4; ++i) {
    int oc = oc_base + ty + 16 * i;
    float f = (float)(acc[i] + (double)bias[oc]);
    xt[(size_t)(p_base + tx) * 256 + oc] = f > 0.f ? f : 0.f;
  }
}

// ---------------- 1x1 heads (cls 3ch, reg 12ch), fp64 acc -------------------
__global__ __launch_bounds__(256) void heads_k(
    const float* __restrict__ x0t, const float* __restrict__ x1t,
    const float* __restrict__ cls_w, const float* __restrict__ cls_b,
    const float* __restrict__ reg_w, const float* __restrict__ reg_b,
    float* __restrict__ cls0, float* __restrict__ reg0,
    float* __restrict__ cls1, float* __restrict__ reg1)
{
  int tid = blockIdx.x * 256 + threadIdx.x;
  int pid = tid >> 4;
  int o = tid & 15;
  if (o == 15 || pid >= 5120) return;
  const float* xr;
  int b, pin, lvl;
  if (pid < 4096) { lvl = 0; xr = x0t + (size_t)pid * 256; b = pid >> 10; pin = pid & 1023; }
  else { int p1 = pid - 4096; lvl = 1; xr = x1t + (size_t)p1 * 256; b = p1 >> 8; pin = p1 & 255; }
  const float* wr; float bv;
  if (o < 3) { wr = cls_w + o * 256; bv = cls_b[o]; }
  else { int e = o - 3; wr = reg_w + e * 256; bv = reg_b[e]; }
  double acc = 0.0;
  const float4* x4 = (const float4*)xr;
  const float4* w4 = (const float4*)wr;
#pragma unroll 4
  for (int c = 0; c < 64; ++c) {
    float4 xv = x4[c], wv = w4[c];
    acc += (double)xv.x * (double)wv.x + (double)xv.y * (double)wv.y +
           (double)xv.z * (double)wv.z + (double)xv.w * (double)wv.w;
  }
  float out = (float)(acc + (double)bv);
  if (o < 3) {
    if (lvl == 0) cls0[b * 3072 + pin * 3 + o] = out;
    else          cls1[b * 768 + pin * 3 + o] = out;
  } else {
    int e = o - 3, a = e >> 2, d = e & 3;
    if (lvl == 0) reg0[((size_t)b * 3072 + pin * 3 + a) * 4 + d] = out;
    else          reg1[((size_t)b * 768 + pin * 3 + a) * 4 + d] = out;
  }
}

// ---------------- anchor gen + box decode + clamp + sigmoid -----------------
__global__ void decode_k(
    const float* __restrict__ cls0, const float* __restrict__ reg0,
    const float* __restrict__ cls1, const float* __restrict__ reg1,
    float* __restrict__ box0, float* __restrict__ sc0,
    float* __restrict__ box1, float* __restrict__ sc1)
{
  int id = blockIdx.x * 256 + threadIdx.x;
  if (id >= 4 * 3840) return;
  int b = id / 3840, m = id - b * 3840;
  int lvl = (m >= 3072) ? 1 : 0;
  int n = lvl ? (m - 3072) : m;
  int Wd = lvl ? 16 : 32;
  float S = lvl ? 16.f : 8.f;
  double scale = lvl ? 16384.0 : 4096.0;
  int pin = n / 3, a = n - pin * 3;
  int y = pin / Wd, x = pin - y * Wd;
  double ratio = (a == 0) ? 0.5 : (a == 1 ? 1.0 : 2.0);
  float w_a = (float)sqrt(scale / ratio);
  float h_a = (float)sqrt(scale * ratio);
  float cx = ((float)x + 0.5f) * S;
  float cy = ((float)y + 0.5f) * S;
  float x1 = cx - 0.5f * w_a, y1 = cy - 0.5f * h_a;
  float x2 = cx + 0.5f * w_a, y2 = cy + 0.5f * h_a;
  x1 = fminf(fmaxf(x1, 0.f), 256.f); y1 = fminf(fmaxf(y1, 0.f), 256.f);
  x2 = fminf(fmaxf(x2, 0.f), 256.f); y2 = fminf(fmaxf(y2, 0.f), 256.f);
  float wa = x2 - x1, ha = y2 - y1;
  float cxa = x1 + 0.5f * wa, cya = y1 + 0.5f * ha;
  const float* rg = lvl ? &reg1[((size_t)b * 768 + n) * 4] : &reg0[((size_t)b * 3072 + n) * 4];
  float dx = rg[0], dy = rg[1], dw = rg[2], dh = rg[3];
  float ncx = dx * wa + cxa;
  float ncy = dy * ha + cya;
  float nw = expf(dw) * wa;
  float nh = expf(dh) * ha;
  float bx1 = ncx - 0.5f * nw, by1 = ncy - 0.5f * nh;
  float bx2 = ncx + 0.5f * nw, by2 = ncy + 0.5f * nh;
  bx1 = fminf(fmaxf(bx1, 0.f), 256.f); by1 = fminf(fmaxf(by1, 0.f), 256.f);
  bx2 = fminf(fmaxf(bx2, 0.f), 256.f); by2 = fminf(fmaxf(by2, 0.f), 256.f);
  float c = lvl ? cls1[b * 768 + n] : cls0[b * 3072 + n];
  float s = 1.f / (1.f + expf(-c));
  float* bo = lvl ? &box1[((size_t)b * 768 + n) * 4] : &box0[((size_t)b * 3072 + n) * 4];
  bo[0] = bx1; bo[1] = by1; bo[2] = bx2; bo[3] = by2;
  if (lvl) sc1[b * 768 + n] = s; else sc0[b * 3072 + n] = s;
}

// ---------------- stable descending enumeration sort per (batch,level) ------
__global__ __launch_bounds__(256) void sort_level_k(
    const float* __restrict__ sc, const float* __restrict__ box,
    float* __restrict__ ssc, float* __restrict__ sbox, int N, int nblk)
{
  __shared__ float s[3072];
  int b = blockIdx.x / nblk;
  int c = blockIdx.x - b * nblk;
  const float* scb = sc + (size_t)b * N;
  for (int j = threadIdx.x; j < N; j += 256) s[j] = scb[j];
  __syncthreads();
  int i = c * 256 + threadIdx.x;
  float si = s[i];
  int rank = 0;
  for (int j = 0; j < N; ++j) {
    float sj = s[j];
    rank += (sj > si) || (sj == si && j < i);
  }
  ssc[(size_t)b * N + rank] = si;
  float4 bi = ((const float4*)box)[(size_t)b * N + i];
  ((float4*)sbox)[(size_t)b * N + rank] = bi;
}

// ---------------- NMS suppression bitmask (row-major), LDS-staged tile ------
// grid: (words, N/256, 4); block 256. mask[(b*N+i)*words+w] bit jj:
//   "box i suppresses box w*64+jj" (iou>0.7 && w*64+jj > i)
__global__ __launch_bounds__(256) void nms_mask_k(
    const float* __restrict__ sbox, unsigned long long* __restrict__ mask,
    int N, int words)
{
  __shared__ float4 bj[64];
  int w = blockIdx.x;
  int i = blockIdx.y * 256 + threadIdx.x;
  int b = blockIdx.z;
  if (threadIdx.x < 64)
    bj[threadIdx.x] = ((const float4*)sbox)[(size_t)b * N + w * 64 + threadIdx.x];
  __syncthreads();
  float4 bi = ((const float4*)sbox)[(size_t)b * N + i];
  float ai = (bi.z - bi.x) * (bi.w - bi.y);
  unsigned long long m = 0ull;
#pragma unroll 16
  for (int jj = 0; jj < 64; ++jj) {
    int j = w * 64 + jj;
    float4 bv = bj[jj];
    float lx = fmaxf(bi.x, bv.x), ly = fmaxf(bi.y, bv.y);
    float rx = fminf(bi.z, bv.z), ry = fminf(bi.w, bv.w);
    float iw = fmaxf(rx - lx, 0.f), ih = fmaxf(ry - ly, 0.f);
    float inter = iw * ih;
    float aj = (bv.z - bv.x) * (bv.w - bv.y);
    float iou = inter / (ai + aj - inter);   // NaN compares false, matches jnp
    if ((iou > 0.7f) & (j > i)) m |= (1ull << jj);
  }
  mask[((size_t)b * N + i) * words + w] = m;
}

// ---------------- transposed diagonal tiles ---------------------------------
// colD[b*N + q] bit ii: "box tbase+ii suppresses box q" (within q's own tile)
__global__ __launch_bounds__(64) void col_diag_k(
    const float* __restrict__ sbox, unsigned long long* __restrict__ colD, int N)
{
  __shared__ float4 tb[64];
  int t = blockIdx.x, b = blockIdx.y;
  int lane = threadIdx.x;
  tb[lane] = ((const float4*)sbox)[(size_t)b * N + t * 64 + lane];
  __syncthreads();
  float4 bq = tb[lane];
  float aq = (bq.z - bq.x) * (bq.w - bq.y);
  unsigned long long col = 0ull;
#pragma unroll 16
  for (int ii = 0; ii < 64; ++ii) {
    float4 bi = tb[ii];
    float lx = fmaxf(bq.x, bi.x), ly = fmaxf(bq.y, bi.y);
    float rx = fminf(bq.z, bi.z), ry = fminf(bq.w, bi.w);
    float iw = fmaxf(rx - lx, 0.f), ih = fmaxf(ry - ly, 0.f);
    float inter = iw * ih;
    float ai = (bi.z - bi.x) * (bi.w - bi.y);
    float iou = inter / (aq + ai - inter);
    if ((iou > 0.7f) & (lane > ii)) col |= (1ull << ii);
  }
  colD[(size_t)b * N + t * 64 + lane] = col;
}

// ---------------- exact greedy scan: ballot-based, one wave per (b,lvl) -----
__global__ __launch_bounds__(64) void nms_scan_k(
    const float* __restrict__ ssc0, const float* __restrict__ sbox0,
    const unsigned long long* __restrict__ mask0,
    const unsigned long long* __restrict__ colD0,
    const float* __restrict__ ssc1, const float* __restrict__ sbox1,
    const unsigned long long* __restrict__ mask1,
    const unsigned long long* __restrict__ colD1,
    float* __restrict__ cb, float* __restrict__ cs)
{
  int z = blockIdx.x;
  int lvl = z >> 2, b = z & 3;
  int N = lvl ? 768 : 3072;
  int words = lvl ? 12 : 48;
  const float* ssc = lvl ? ssc1 : ssc0;
  const float* sbox = lvl ? sbox1 : sbox0;
  const unsigned long long* mask = (lvl ? mask1 : mask0) + (size_t)b * N * words;
  const unsigned long long* colD = (lvl ? colD1 : colD0) + (size_t)b * N;
  const int lane = threadIdx.x;
  float* cbb = cb + ((size_t)b * 2000 + lvl * 1000) * 4;
  float* csb = cs + (size_t)b * 2000 + lvl * 1000;
  for (int q = lane; q < 1000; q += 64) {
    csb[q] = -1.f;
    ((float4*)cbb)[q] = make_float4(-1.f, -1.f, -1.f, -1.f);
  }
  unsigned long long removed = 0ull;   // lane w (< words) holds removed word w
  int kept_base = 0;
  for (int t = 0; t < words; ++t) {
    unsigned long long wr = __shfl(removed, t);
    unsigned long long col = colD[t * 64 + lane];   // who suppresses me (in-tile)
    bool sup = (wr >> lane) & 1ull;
    // serial greedy: 64 steps, pure VALU/ballot on the chain
#pragma unroll
    for (int i = 0; i < 64; ++i) {
      unsigned long long supv = __ballot(sup);
      bool keep_i = !((supv >> i) & 1ull);
      sup = sup | (keep_i & ((col >> i) & 1ull));
    }
    unsigned long long keep64 = ~__ballot(sup);
    // emit kept boxes
    if (!sup) {
      int rank = kept_base + __popcll(keep64 & ((1ull << lane) - 1ull));
      if (rank < 1000) {
        int i = t * 64 + lane;
        csb[rank] = ssc[(size_t)b * N + i];
        ((float4*)cbb)[rank] = ((const float4*)sbox)[(size_t)b * N + i];
      }
    }
    // propagate suppression to future word-columns (coalesced across lanes)
    if (lane > t && lane < words) {
      const unsigned long long* row = mask + (size_t)t * 64 * words + lane;
      unsigned long long acc = removed;
#pragma unroll 16
      for (int bb = 0; bb < 64; ++bb) {
        unsigned long long m = row[(size_t)bb * words];
        acc |= (((keep64 >> bb) & 1ull) ? m : 0ull);
      }
      removed = acc;
    }
    kept_base += __popcll(keep64);
  }
}

// ---------------- final stable descending sort of 2000, gather boxes --------
__global__ __launch_bounds__(256) void final_sort_k(
    const float* __restrict__ cs, const float* __restrict__ cb,
    float* __restrict__ out)
{
  __shared__ float s[2000];
  int b = blockIdx.x >> 3, c = blockIdx.x & 7;
  const float* csb = cs + (size_t)b * 2000;
  for (int j = threadIdx.x; j < 2000; j += 256) s[j] = csb[j];
  __syncthreads();
  if (threadIdx.x >= 250) return;
  int li = c * 250 + threadIdx.x;
  float si = s[li];
  int rank = 0;
  for (int j = 0; j < 2000; ++j) {
    float sj = s[j];
    rank += (sj > si) || (sj == si && j < li);
  }
  float4 bi = ((const float4*)cb)[(size_t)b * 2000 + li];
  ((float4*)out)[(size_t)b * 2000 + rank] = bi;
}

// ============================================================================
extern "C" void kernel_launch(void* const* d_in, const int* in_sizes, int n_in,
                              void* d_out, int out_size, void* d_ws, size_t ws_size,
                              hipStream_t stream) {
  const float* feat0  = (const float*)d_in[0];
  const float* feat1  = (const float*)d_in[1];
  const float* conv_w = (const float*)d_in[2];
  const float* conv_b = (const float*)d_in[3];
  const float* cls_w  = (const float*)d_in[4];
  const float* cls_b  = (const float*)d_in[5];
  const float* reg_w  = (const float*)d_in[6];
  const float* reg_b  = (const float*)d_in[7];

  char* p = (char*)d_ws;
  auto alloc = [&](size_t bytes) {
    char* r = p;
    p += (bytes + 255) & ~(size_t)255;
    return r;
  };
  float* w_t  = (float*)alloc((size_t)2304 * 256 * 4);
  float* x0t  = (float*)alloc((size_t)4096 * 256 * 4);
  float* x1t  = (float*)alloc((size_t)1024 * 256 * 4);
  float* cls0 = (float*)alloc((size_t)4 * 3072 * 4);
  float* reg0 = (float*)alloc((size_t)4 * 3072 * 16);
  float* cls1 = (float*)alloc((size_t)4 * 768 * 4);
  float* reg1 = (float*)alloc((size_t)4 * 768 * 16);
  float* box0 = (float*)alloc((size_t)4 * 3072 * 16);
  float* sc0  = (float*)alloc((size_t)4 * 3072 * 4);
  float* box1 = (float*)alloc((size_t)4 * 768 * 16);
  float* sc1  = (float*)alloc((size_t)4 * 768 * 4);
  float* sbox0 = (float*)alloc((size_t)4 * 3072 * 16);
  float* ssc0  = (float*)alloc((size_t)4 * 3072 * 4);
  float* sbox1 = (float*)alloc((size_t)4 * 768 * 16);
  float* ssc1  = (float*)alloc((size_t)4 * 768 * 4);
  unsigned long long* mask0 = (unsigned long long*)alloc((size_t)4 * 3072 * 48 * 8);
  unsigned long long* mask1 = (unsigned long long*)alloc((size_t)4 * 768 * 12 * 8);
  unsigned long long* colD0 = (unsigned long long*)alloc((size_t)4 * 3072 * 8);
  unsigned long long* colD1 = (unsigned long long*)alloc((size_t)4 * 768 * 8);
  float* cb = (float*)alloc((size_t)4 * 2000 * 16);
  float* cs = (float*)alloc((size_t)4 * 2000 * 4);

  transpose_w_k<<<(2304 * 256 + 255) / 256, 256, 0, stream>>>(conv_w, w_t);
  conv3_gemm<32, 32><<<dim3(4, 64), 256, 0, stream>>>(feat0, w_t, conv_b, x0t);
  conv3_gemm_n16<16, 16><<<dim3(4, 64), 256, 0, stream>>>(feat1, w_t, conv_b, x1t);
  heads_k<<<320, 256, 0, stream>>>(x0t, x1t, cls_w, cls_b, reg_w, reg_b,
                                   cls0, reg0, cls1, reg1);
  decode_k<<<(4 * 3840 + 255) / 256, 256, 0, stream>>>(cls0, reg0, cls1, reg1,
                                                       box0, sc0, box1, sc1);
  sort_level_k<<<4 * 12, 256, 0, stream>>>(sc0, box0, ssc0, sbox0, 3072, 12);
  sort_level_k<<<4 * 3, 256, 0, stream>>>(sc1, box1, ssc1, sbox1, 768, 3);
  nms_mask_k<<<dim3(48, 12, 4), 256, 0, stream>>>(sbox0, mask0, 3072, 48);
  nms_mask_k<<<dim3(12, 3, 4), 256, 0, stream>>>(sbox1, mask1, 768, 12);
  col_diag_k<<<dim3(48, 4), 64, 0, stream>>>(sbox0, colD0, 3072);
  col_diag_k<<<dim3(12, 4), 64, 0, stream>>>(sbox1, colD1, 768);
  nms_scan_k<<<8, 64, 0, stream>>>(ssc0, sbox0, mask0, colD0,
                                   ssc1, sbox1, mask1, colD1, cb, cs);
  final_sort_k<<<32, 256, 0, stream>>>(cs, cb, (float*)d_out);
}

// Round 3
// 757.186 us; speedup vs baseline: 2.1438x; 1.4170x over previous
//
#include <hip/hip_runtime.h>
#include <math.h>

// ============================================================================
// RPN pipeline for MI355X.
// L0: H=W=32, stride 8, scale 4096 ; L1: H=W=16, stride 16, scale 16384
// A=3 ratios {0.5,1,2}. N0=3072, N1=768 anchors/batch. BS=4.
// Numeric recipe (validated bitwise in R1/R2): fp64 accumulation everywhere a
// sum feeds the score/box path, fp32 rounding at layer boundaries, fp32
// expf/sigmoid. fp64 order is free (1e-16 error vs 1e-7 fp32 ulp margin),
// so split-K + deterministic reduce is safe.
// R3: conv split-K (KS=3) -> 768/384 blocks (was 256 = 1 wave/SIMD, VALUBusy
// 19%). Partial fp64 buffers + reduce(bias,ReLU) kernel.
// ============================================================================

__global__ void transpose_w_k(const float* __restrict__ w, float* __restrict__ wt) {
  int idx = blockIdx.x * 256 + threadIdx.x;
  if (idx >= 2304 * 256) return;
  int k = idx >> 8, oc = idx & 255;
  wt[idx] = w[oc * 2304 + k];
}

// ---------------- conv3x3 as implicit GEMM, split-K, fp64 partials ----------
// grid: (oc_tiles=4, p_tiles, KS). part[kchunk][p][oc] fp64, no bias/relu.
template <int H, int W, int PT, int KCH>
__global__ __launch_bounds__(256) void conv3_gemm_sk(
    const float* __restrict__ feat,   // [4][256][H][W]
    const float* __restrict__ wt,     // [2304][256]
    double* __restrict__ part)        // [KS][M][256], M = 4*H*W
{
  constexpr int HW = H * W;
  constexpr int M = 4 * HW;
  constexpr int PJ = PT / 16;
  __shared__ double Ald[16][64];
  __shared__ double Bld[16][PT];
  const int t = threadIdx.x;
  const int tx = t & 15, ty = t >> 4;
  const int oc_base = blockIdx.x * 64;
  const int p_base  = blockIdx.y * PT;
  const int k_base  = blockIdx.z * KCH;
  double acc[4][PJ] = {};
  for (int k0 = k_base; k0 < k_base + KCH; k0 += 16) {
#pragma unroll
    for (int r = 0; r < 4; ++r) {                    // stage A (weights 16x64)
      int e = t + r * 256;
      int kk = e >> 6, ocl = e & 63;
      Ald[kk][ocl] = (double)wt[(k0 + kk) * 256 + oc_base + ocl];
    }
#pragma unroll
    for (int r = 0; r < 16 * PT / 256; ++r) {        // stage B (im2col 16xPT)
      int e = t + r * 256;
      int kk = e / PT, pxl = e % PT;
      int p = p_base + pxl;
      int b = p / HW, pin = p % HW;
      int y = pin / W, x = pin % W;
      int k = k0 + kk;
      int ic = k / 9, rr = k - ic * 9;
      int ky = rr / 3, kx = rr - ky * 3;
      int iy = y + ky - 1, ix = x + kx - 1;
      float v = 0.f;
      if ((unsigned)iy < (unsigned)H && (unsigned)ix < (unsigned)W)
        v = feat[((b * 256 + ic) * H + iy) * W + ix];
      Bld[kk][pxl] = (double)v;
    }
    __syncthreads();
#pragma unroll
    for (int kk = 0; kk < 16; ++kk) {
      double a[4], bb[PJ];
#pragma unroll
      for (int i = 0; i < 4; ++i) a[i] = Ald[kk][ty + 16 * i];
#pragma unroll
      for (int j = 0; j < PJ; ++j) bb[j] = Bld[kk][tx + 16 * j];
#pragma unroll
      for (int i = 0; i < 4; ++i)
#pragma unroll
        for (int j = 0; j < PJ; ++j) acc[i][j] += a[i] * bb[j];
    }
    __syncthreads();
  }
  double* pp = part + (size_t)blockIdx.z * M * 256;
#pragma unroll
  for (int i = 0; i < 4; ++i) {
    int oc = oc_base + ty + 16 * i;
#pragma unroll
    for (int j = 0; j < PJ; ++j) {
      int p = p_base + tx + 16 * j;
      pp[(size_t)p * 256 + oc] = acc[i][j];
    }
  }
}

// ---------------- reduce partials + bias + ReLU -> fp32 x^T -----------------
template <int KS>
__global__ void reduce_relu_k(const double* __restrict__ part,
                              const float* __restrict__ bias,
                              float* __restrict__ xt, int M)
{
  int idx = blockIdx.x * 256 + threadIdx.x;
  if (idx >= M * 256) return;
  int oc = idx & 255;
  double s = (double)bias[oc];
#pragma unroll
  for (int c = 0; c < KS; ++c) s += part[(size_t)c * M * 256 + idx];
  float f = (float)s;
  xt[idx] = f > 0.f ? f : 0.f;
}

// ---------------- 1x1 heads (cls 3ch, reg 12ch), fp64 acc -------------------
__global__ __launch_bounds__(256) void heads_k(
    const float* __restrict__ x0t, const float* __restrict__ x1t,
    const float* __restrict__ cls_w, const float* __restrict__ cls_b,
    const float* __restrict__ reg_w, const float* __restrict__ reg_b,
    float* __restrict__ cls0, float* __restrict__ reg0,
    float* __restrict__ cls1, float* __restrict__ reg1)
{
  int tid = blockIdx.x * 256 + threadIdx.x;
  int pid = tid >> 4;
  int o = tid & 15;
  if (o == 15 || pid >= 5120) return;
  const float* xr;
  int b, pin, lvl;
  if (pid < 4096) { lvl = 0; xr = x0t + (size_t)pid * 256; b = pid >> 10; pin = pid & 1023; }
  else { int p1 = pid - 4096; lvl = 1; xr = x1t + (size_t)p1 * 256; b = p1 >> 8; pin = p1 & 255; }
  const float* wr; float bv;
  if (o < 3) { wr = cls_w + o * 256; bv = cls_b[o]; }
  else { int e = o - 3; wr = reg_w + e * 256; bv = reg_b[e]; }
  double acc = 0.0;
  const float4* x4 = (const float4*)xr;
  const float4* w4 = (const float4*)wr;
#pragma unroll 4
  for (int c = 0; c < 64; ++c) {
    float4 xv = x4[c], wv = w4[c];
    acc += (double)xv.x * (double)wv.x + (double)xv.y * (double)wv.y +
           (double)xv.z * (double)wv.z + (double)xv.w * (double)wv.w;
  }
  float out = (float)(acc + (double)bv);
  if (o < 3) {
    if (lvl == 0) cls0[b * 3072 + pin * 3 + o] = out;
    else          cls1[b * 768 + pin * 3 + o] = out;
  } else {
    int e = o - 3, a = e >> 2, d = e & 3;
    if (lvl == 0) reg0[((size_t)b * 3072 + pin * 3 + a) * 4 + d] = out;
    else          reg1[((size_t)b * 768 + pin * 3 + a) * 4 + d] = out;
  }
}

// ---------------- anchor gen + box decode + clamp + sigmoid -----------------
__global__ void decode_k(
    const float* __restrict__ cls0, const float* __restrict__ reg0,
    const float* __restrict__ cls1, const float* __restrict__ reg1,
    float* __restrict__ box0, float* __restrict__ sc0,
    float* __restrict__ box1, float* __restrict__ sc1)
{
  int id = blockIdx.x * 256 + threadIdx.x;
  if (id >= 4 * 3840) return;
  int b = id / 3840, m = id - b * 3840;
  int lvl = (m >= 3072) ? 1 : 0;
  int n = lvl ? (m - 3072) : m;
  int Wd = lvl ? 16 : 32;
  float S = lvl ? 16.f : 8.f;
  double scale = lvl ? 16384.0 : 4096.0;
  int pin = n / 3, a = n - pin * 3;
  int y = pin / Wd, x = pin - y * Wd;
  double ratio = (a == 0) ? 0.5 : (a == 1 ? 1.0 : 2.0);
  float w_a = (float)sqrt(scale / ratio);
  float h_a = (float)sqrt(scale * ratio);
  float cx = ((float)x + 0.5f) * S;
  float cy = ((float)y + 0.5f) * S;
  float x1 = cx - 0.5f * w_a, y1 = cy - 0.5f * h_a;
  float x2 = cx + 0.5f * w_a, y2 = cy + 0.5f * h_a;
  x1 = fminf(fmaxf(x1, 0.f), 256.f); y1 = fminf(fmaxf(y1, 0.f), 256.f);
  x2 = fminf(fmaxf(x2, 0.f), 256.f); y2 = fminf(fmaxf(y2, 0.f), 256.f);
  float wa = x2 - x1, ha = y2 - y1;
  float cxa = x1 + 0.5f * wa, cya = y1 + 0.5f * ha;
  const float* rg = lvl ? &reg1[((size_t)b * 768 + n) * 4] : &reg0[((size_t)b * 3072 + n) * 4];
  float dx = rg[0], dy = rg[1], dw = rg[2], dh = rg[3];
  float ncx = dx * wa + cxa;
  float ncy = dy * ha + cya;
  float nw = expf(dw) * wa;
  float nh = expf(dh) * ha;
  float bx1 = ncx - 0.5f * nw, by1 = ncy - 0.5f * nh;
  float bx2 = ncx + 0.5f * nw, by2 = ncy + 0.5f * nh;
  bx1 = fminf(fmaxf(bx1, 0.f), 256.f); by1 = fminf(fmaxf(by1, 0.f), 256.f);
  bx2 = fminf(fmaxf(bx2, 0.f), 256.f); by2 = fminf(fmaxf(by2, 0.f), 256.f);
  float c = lvl ? cls1[b * 768 + n] : cls0[b * 3072 + n];
  float s = 1.f / (1.f + expf(-c));
  float* bo = lvl ? &box1[((size_t)b * 768 + n) * 4] : &box0[((size_t)b * 3072 + n) * 4];
  bo[0] = bx1; bo[1] = by1; bo[2] = bx2; bo[3] = by2;
  if (lvl) sc1[b * 768 + n] = s; else sc0[b * 3072 + n] = s;
}

// ---------------- stable descending enumeration sort per (batch,level) ------
__global__ __launch_bounds__(256) void sort_level_k(
    const float* __restrict__ sc, const float* __restrict__ box,
    float* __restrict__ ssc, float* __restrict__ sbox, int N, int nblk)
{
  __shared__ float s[3072];
  int b = blockIdx.x / nblk;
  int c = blockIdx.x - b * nblk;
  const float* scb = sc + (size_t)b * N;
  for (int j = threadIdx.x; j < N; j += 256) s[j] = scb[j];
  __syncthreads();
  int i = c * 256 + threadIdx.x;
  float si = s[i];
  int rank = 0;
  for (int j = 0; j < N; ++j) {
    float sj = s[j];
    rank += (sj > si) || (sj == si && j < i);
  }
  ssc[(size_t)b * N + rank] = si;
  float4 bi = ((const float4*)box)[(size_t)b * N + i];
  ((float4*)sbox)[(size_t)b * N + rank] = bi;
}

// ---------------- NMS suppression bitmask (row-major), LDS-staged tile ------
__global__ __launch_bounds__(256) void nms_mask_k(
    const float* __restrict__ sbox, unsigned long long* __restrict__ mask,
    int N, int words)
{
  __shared__ float4 bj[64];
  int w = blockIdx.x;
  int i = blockIdx.y * 256 + threadIdx.x;
  int b = blockIdx.z;
  if (threadIdx.x < 64)
    bj[threadIdx.x] = ((const float4*)sbox)[(size_t)b * N + w * 64 + threadIdx.x];
  __syncthreads();
  float4 bi = ((const float4*)sbox)[(size_t)b * N + i];
  float ai = (bi.z - bi.x) * (bi.w - bi.y);
  unsigned long long m = 0ull;
#pragma unroll 16
  for (int jj = 0; jj < 64; ++jj) {
    int j = w * 64 + jj;
    float4 bv = bj[jj];
    float lx = fmaxf(bi.x, bv.x), ly = fmaxf(bi.y, bv.y);
    float rx = fminf(bi.z, bv.z), ry = fminf(bi.w, bv.w);
    float iw = fmaxf(rx - lx, 0.f), ih = fmaxf(ry - ly, 0.f);
    float inter = iw * ih;
    float aj = (bv.z - bv.x) * (bv.w - bv.y);
    float iou = inter / (ai + aj - inter);   // NaN compares false, matches jnp
    if ((iou > 0.7f) & (j > i)) m |= (1ull << jj);
  }
  mask[((size_t)b * N + i) * words + w] = m;
}

// ---------------- transposed diagonal tiles ---------------------------------
__global__ __launch_bounds__(64) void col_diag_k(
    const float* __restrict__ sbox, unsigned long long* __restrict__ colD, int N)
{
  __shared__ float4 tb[64];
  int t = blockIdx.x, b = blockIdx.y;
  int lane = threadIdx.x;
  tb[lane] = ((const float4*)sbox)[(size_t)b * N + t * 64 + lane];
  __syncthreads();
  float4 bq = tb[lane];
  float aq = (bq.z - bq.x) * (bq.w - bq.y);
  unsigned long long col = 0ull;
#pragma unroll 16
  for (int ii = 0; ii < 64; ++ii) {
    float4 bi = tb[ii];
    float lx = fmaxf(bq.x, bi.x), ly = fmaxf(bq.y, bi.y);
    float rx = fminf(bq.z, bi.z), ry = fminf(bq.w, bi.w);
    float iw = fmaxf(rx - lx, 0.f), ih = fmaxf(ry - ly, 0.f);
    float inter = iw * ih;
    float ai = (bi.z - bi.x) * (bi.w - bi.y);
    float iou = inter / (aq + ai - inter);
    if ((iou > 0.7f) & (lane > ii)) col |= (1ull << ii);
  }
  colD[(size_t)b * N + t * 64 + lane] = col;
}

// ---------------- exact greedy scan: ballot-based, one wave per (b,lvl) -----
__global__ __launch_bounds__(64) void nms_scan_k(
    const float* __restrict__ ssc0, const float* __restrict__ sbox0,
    const unsigned long long* __restrict__ mask0,
    const unsigned long long* __restrict__ colD0,
    const float* __restrict__ ssc1, const float* __restrict__ sbox1,
    const unsigned long long* __restrict__ mask1,
    const unsigned long long* __restrict__ colD1,
    float* __restrict__ cb, float* __restrict__ cs)
{
  int z = blockIdx.x;
  int lvl = z >> 2, b = z & 3;
  int N = lvl ? 768 : 3072;
  int words = lvl ? 12 : 48;
  const float* ssc = lvl ? ssc1 : ssc0;
  const float* sbox = lvl ? sbox1 : sbox0;
  const unsigned long long* mask = (lvl ? mask1 : mask0) + (size_t)b * N * words;
  const unsigned long long* colD = (lvl ? colD1 : colD0) + (size_t)b * N;
  const int lane = threadIdx.x;
  float* cbb = cb + ((size_t)b * 2000 + lvl * 1000) * 4;
  float* csb = cs + (size_t)b * 2000 + lvl * 1000;
  for (int q = lane; q < 1000; q += 64) {
    csb[q] = -1.f;
    ((float4*)cbb)[q] = make_float4(-1.f, -1.f, -1.f, -1.f);
  }
  unsigned long long removed = 0ull;   // lane w (< words) holds removed word w
  int kept_base = 0;
  for (int t = 0; t < words; ++t) {
    unsigned long long wr = __shfl(removed, t);
    unsigned long long col = colD[t * 64 + lane];
    bool sup = (wr >> lane) & 1ull;
#pragma unroll
    for (int i = 0; i < 64; ++i) {                  // pure VALU/ballot chain
      unsigned long long supv = __ballot(sup);
      bool keep_i = !((supv >> i) & 1ull);
      sup = sup | (keep_i & ((col >> i) & 1ull));
    }
    unsigned long long keep64 = ~__ballot(sup);
    if (!sup) {
      int rank = kept_base + __popcll(keep64 & ((1ull << lane) - 1ull));
      if (rank < 1000) {
        int i = t * 64 + lane;
        csb[rank] = ssc[(size_t)b * N + i];
        ((float4*)cbb)[rank] = ((const float4*)sbox)[(size_t)b * N + i];
      }
    }
    if (lane > t && lane < words) {                 // propagate suppression
      const unsigned long long* row = mask + (size_t)t * 64 * words + lane;
      unsigned long long acc = removed;
#pragma unroll 16
      for (int bb = 0; bb < 64; ++bb) {
        unsigned long long m = row[(size_t)bb * words];
        acc |= (((keep64 >> bb) & 1ull) ? m : 0ull);
      }
      removed = acc;
    }
    kept_base += __popcll(keep64);
  }
}

// ---------------- final stable descending sort of 2000, gather boxes --------
__global__ __launch_bounds__(256) void final_sort_k(
    const float* __restrict__ cs, const float* __restrict__ cb,
    float* __restrict__ out)
{
  __shared__ float s[2000];
  int b = blockIdx.x >> 3, c = blockIdx.x & 7;
  const float* csb = cs + (size_t)b * 2000;
  for (int j = threadIdx.x; j < 2000; j += 256) s[j] = csb[j];
  __syncthreads();
  if (threadIdx.x >= 250) return;
  int li = c * 250 + threadIdx.x;
  float si = s[li];
  int rank = 0;
  for (int j = 0; j < 2000; ++j) {
    float sj = s[j];
    rank += (sj > si) || (sj == si && j < li);
  }
  float4 bi = ((const float4*)cb)[(size_t)b * 2000 + li];
  ((float4*)out)[(size_t)b * 2000 + rank] = bi;
}

// ============================================================================
extern "C" void kernel_launch(void* const* d_in, const int* in_sizes, int n_in,
                              void* d_out, int out_size, void* d_ws, size_t ws_size,
                              hipStream_t stream) {
  const float* feat0  = (const float*)d_in[0];
  const float* feat1  = (const float*)d_in[1];
  const float* conv_w = (const float*)d_in[2];
  const float* conv_b = (const float*)d_in[3];
  const float* cls_w  = (const float*)d_in[4];
  const float* cls_b  = (const float*)d_in[5];
  const float* reg_w  = (const float*)d_in[6];
  const float* reg_b  = (const float*)d_in[7];

  char* p = (char*)d_ws;
  auto alloc = [&](size_t bytes) {
    char* r = p;
    p += (bytes + 255) & ~(size_t)255;
    return r;
  };
  float* w_t  = (float*)alloc((size_t)2304 * 256 * 4);
  float* x0t  = (float*)alloc((size_t)4096 * 256 * 4);
  float* x1t  = (float*)alloc((size_t)1024 * 256 * 4);
  double* part0 = (double*)alloc((size_t)3 * 4096 * 256 * 8);   // 25.2 MB
  double* part1 = (double*)alloc((size_t)3 * 1024 * 256 * 8);   //  6.3 MB
  float* cls0 = (float*)alloc((size_t)4 * 3072 * 4);
  float* reg0 = (float*)alloc((size_t)4 * 3072 * 16);
  float* cls1 = (float*)alloc((size_t)4 * 768 * 4);
  float* reg1 = (float*)alloc((size_t)4 * 768 * 16);
  float* box0 = (float*)alloc((size_t)4 * 3072 * 16);
  float* sc0  = (float*)alloc((size_t)4 * 3072 * 4);
  float* box1 = (float*)alloc((size_t)4 * 768 * 16);
  float* sc1  = (float*)alloc((size_t)4 * 768 * 4);
  float* sbox0 = (float*)alloc((size_t)4 * 3072 * 16);
  float* ssc0  = (float*)alloc((size_t)4 * 3072 * 4);
  float* sbox1 = (float*)alloc((size_t)4 * 768 * 16);
  float* ssc1  = (float*)alloc((size_t)4 * 768 * 4);
  unsigned long long* mask0 = (unsigned long long*)alloc((size_t)4 * 3072 * 48 * 8);
  unsigned long long* mask1 = (unsigned long long*)alloc((size_t)4 * 768 * 12 * 8);
  unsigned long long* colD0 = (unsigned long long*)alloc((size_t)4 * 3072 * 8);
  unsigned long long* colD1 = (unsigned long long*)alloc((size_t)4 * 768 * 8);
  float* cb = (float*)alloc((size_t)4 * 2000 * 16);
  float* cs = (float*)alloc((size_t)4 * 2000 * 4);

  transpose_w_k<<<(2304 * 256 + 255) / 256, 256, 0, stream>>>(conv_w, w_t);
  // L0: 64px tiles, KS=3 (K-chunk 768) -> 4*16*3... grid (4, 4096/64=64, 3)=768 blocks
  conv3_gemm_sk<32, 32, 64, 768><<<dim3(4, 64, 3), 256, 0, stream>>>(feat0, w_t, part0);
  // L1: 32px tiles, KS=3 -> grid (4, 1024/32=32, 3)=384 blocks
  conv3_gemm_sk<16, 16, 32, 768><<<dim3(4, 32, 3), 256, 0, stream>>>(feat1, w_t, part1);
  reduce_relu_k<3><<<(4096 * 256 + 255) / 256, 256, 0, stream>>>(part0, conv_b, x0t, 4096);
  reduce_relu_k<3><<<(1024 * 256 + 255) / 256, 256, 0, stream>>>(part1, conv_b, x1t, 1024);
  heads_k<<<320, 256, 0, stream>>>(x0t, x1t, cls_w, cls_b, reg_w, reg_b,
                                   cls0, reg0, cls1, reg1);
  decode_k<<<(4 * 3840 + 255) / 256, 256, 0, stream>>>(cls0, reg0, cls1, reg1,
                                                       box0, sc0, box1, sc1);
  sort_level_k<<<4 * 12, 256, 0, stream>>>(sc0, box0, ssc0, sbox0, 3072, 12);
  sort_level_k<<<4 * 3, 256, 0, stream>>>(sc1, box1, ssc1, sbox1, 768, 3);
  nms_mask_k<<<dim3(48, 12, 4), 256, 0, stream>>>(sbox0, mask0, 3072, 48);
  nms_mask_k<<<dim3(12, 3, 4), 256, 0, stream>>>(sbox1, mask1, 768, 12);
  col_diag_k<<<dim3(48, 4), 64, 0, stream>>>(sbox0, colD0, 3072);
  col_diag_k<<<dim3(12, 4), 64, 0, stream>>>(sbox1, colD1, 768);
  nms_scan_k<<<8, 64, 0, stream>>>(ssc0, sbox0, mask0, colD0,
                                   ssc1, sbox1, mask1, colD1, cb, cs);
  final_sort_k<<<32, 256, 0, stream>>>(cs, cb, (float*)d_out);
}

// Round 4
// 679.295 us; speedup vs baseline: 2.3896x; 1.1147x over previous
//
#include <hip/hip_runtime.h>
#include <math.h>

// ============================================================================
// RPN pipeline for MI355X.
// L0: H=W=32, stride 8, scale 4096 ; L1: H=W=16, stride 16, scale 16384
// A=3 ratios {0.5,1,2}. N0=3072, N1=768 anchors/batch. BS=4.
// Numeric recipe (validated bitwise R1-R3): fp64 accumulation wherever a sum
// feeds the score/box path, fp32 rounding at layer boundaries, fp32 expf.
// fp64 regrouping is free (1e-16 vs 1e-7 fp32 ulp margin) -> split-K safe.
// R4: single merged conv kernel, both levels: 1024 L0-blocks (KS=4) + 512
// L1-blocks (PT=64, KS=8) = 1536 blocks = 6/CU = 24 waves/CU. Fixes both the
// L0 grid-limit (was 768 blocks, VALUBusy 44%) and the hidden L1 conv
// (384 blocks, ~18% occupancy ceiling).
// ============================================================================

__global__ void transpose_w_k(const float* __restrict__ w, float* __restrict__ wt) {
  int idx = blockIdx.x * 256 + threadIdx.x;
  if (idx >= 2304 * 256) return;
  int k = idx >> 8, oc = idx & 255;
  wt[idx] = w[oc * 2304 + k];
}

// ---------------- merged conv3x3 implicit GEMM, split-K, fp64 partials ------
// bid < 1024: L0 (oc_t 4, p_t 64, kc 4, KCH=576=36 ktiles)
// bid >= 1024: L1 (oc_t 4, p_t 16, kc 8, KCH=288=18 ktiles)
__global__ __launch_bounds__(256) void conv3_sk_u(
    const float* __restrict__ feat0, const float* __restrict__ feat1,
    const float* __restrict__ wt,
    double* __restrict__ part0, double* __restrict__ part1)
{
  __shared__ double Ald[16][64];
  __shared__ double Bld[16][64];
  const int t = threadIdx.x;
  const int tx = t & 15, ty = t >> 4;
  const int bid = blockIdx.x;
  const float* feat;
  double* part;
  int oc_t, p_t, ktiles, k_base, hw_sh, w_sh, H;
  if (bid < 1024) {
    int kc = bid >> 8;
    feat = feat0; part = part0 + (size_t)kc * 4096 * 256;
    oc_t = bid & 3; p_t = (bid >> 2) & 63;
    k_base = kc * 576; ktiles = 36; hw_sh = 10; w_sh = 5; H = 32;
  } else {
    int b2 = bid - 1024;
    int kc = b2 >> 6;
    feat = feat1; part = part1 + (size_t)kc * 1024 * 256;
    oc_t = b2 & 3; p_t = (b2 >> 2) & 15;
    k_base = kc * 288; ktiles = 18; hw_sh = 8; w_sh = 4; H = 16;
  }
  const int oc_base = oc_t * 64;
  const int p_base  = p_t * 64;
  const int wmask = H - 1, hwmask = (1 << hw_sh) - 1;
  double acc[4][4] = {};
  for (int kt = 0; kt < ktiles; ++kt) {
    const int k0 = k_base + kt * 16;
#pragma unroll
    for (int r = 0; r < 4; ++r) {                    // stage A (weights 16x64)
      int e = t + r * 256;
      int kk = e >> 6, ocl = e & 63;
      Ald[kk][ocl] = (double)wt[(k0 + kk) * 256 + oc_base + ocl];
    }
#pragma unroll
    for (int r = 0; r < 4; ++r) {                    // stage B (im2col 16x64)
      int e = t + r * 256;
      int kk = e >> 6, pxl = e & 63;
      int p = p_base + pxl;
      int b = p >> hw_sh, pin = p & hwmask;
      int y = pin >> w_sh, x = pin & wmask;
      int k = k0 + kk;
      int ic = k / 9, rr = k - ic * 9;
      int ky = rr / 3, kx = rr - ky * 3;
      int iy = y + ky - 1, ix = x + kx - 1;
      float v = 0.f;
      if ((unsigned)iy < (unsigned)H && (unsigned)ix < (unsigned)H)
        v = feat[(((b << 8) + ic) << hw_sh) + (iy << w_sh) + ix];
      Bld[kk][pxl] = (double)v;
    }
    __syncthreads();
#pragma unroll
    for (int kk = 0; kk < 16; ++kk) {
      double a[4], bb[4];
#pragma unroll
      for (int i = 0; i < 4; ++i) a[i] = Ald[kk][ty + 16 * i];
#pragma unroll
      for (int j = 0; j < 4; ++j) bb[j] = Bld[kk][tx + 16 * j];
#pragma unroll
      for (int i = 0; i < 4; ++i)
#pragma unroll
        for (int j = 0; j < 4; ++j) acc[i][j] += a[i] * bb[j];
    }
    __syncthreads();
  }
#pragma unroll
  for (int i = 0; i < 4; ++i) {
    int oc = oc_base + ty + 16 * i;
#pragma unroll
    for (int j = 0; j < 4; ++j) {
      int p = p_base + tx + 16 * j;
      part[(size_t)p * 256 + oc] = acc[i][j];
    }
  }
}

// ---------------- reduce partials + bias + ReLU -> fp32 x^T -----------------
template <int KS>
__global__ void reduce_relu_k(const double* __restrict__ part,
                              const float* __restrict__ bias,
                              float* __restrict__ xt, int M)
{
  int idx = blockIdx.x * 256 + threadIdx.x;
  if (idx >= M * 256) return;
  int oc = idx & 255;
  double s = (double)bias[oc];
#pragma unroll
  for (int c = 0; c < KS; ++c) s += part[(size_t)c * M * 256 + idx];
  float f = (float)s;
  xt[idx] = f > 0.f ? f : 0.f;
}

// ---------------- 1x1 heads (cls 3ch, reg 12ch), fp64 acc -------------------
__global__ __launch_bounds__(256) void heads_k(
    const float* __restrict__ x0t, const float* __restrict__ x1t,
    const float* __restrict__ cls_w, const float* __restrict__ cls_b,
    const float* __restrict__ reg_w, const float* __restrict__ reg_b,
    float* __restrict__ cls0, float* __restrict__ reg0,
    float* __restrict__ cls1, float* __restrict__ reg1)
{
  int tid = blockIdx.x * 256 + threadIdx.x;
  int pid = tid >> 4;
  int o = tid & 15;
  if (o == 15 || pid >= 5120) return;
  const float* xr;
  int b, pin, lvl;
  if (pid < 4096) { lvl = 0; xr = x0t + (size_t)pid * 256; b = pid >> 10; pin = pid & 1023; }
  else { int p1 = pid - 4096; lvl = 1; xr = x1t + (size_t)p1 * 256; b = p1 >> 8; pin = p1 & 255; }
  const float* wr; float bv;
  if (o < 3) { wr = cls_w + o * 256; bv = cls_b[o]; }
  else { int e = o - 3; wr = reg_w + e * 256; bv = reg_b[e]; }
  double acc = 0.0;
  const float4* x4 = (const float4*)xr;
  const float4* w4 = (const float4*)wr;
#pragma unroll 4
  for (int c = 0; c < 64; ++c) {
    float4 xv = x4[c], wv = w4[c];
    acc += (double)xv.x * (double)wv.x + (double)xv.y * (double)wv.y +
           (double)xv.z * (double)wv.z + (double)xv.w * (double)wv.w;
  }
  float out = (float)(acc + (double)bv);
  if (o < 3) {
    if (lvl == 0) cls0[b * 3072 + pin * 3 + o] = out;
    else          cls1[b * 768 + pin * 3 + o] = out;
  } else {
    int e = o - 3, a = e >> 2, d = e & 3;
    if (lvl == 0) reg0[((size_t)b * 3072 + pin * 3 + a) * 4 + d] = out;
    else          reg1[((size_t)b * 768 + pin * 3 + a) * 4 + d] = out;
  }
}

// ---------------- anchor gen + box decode + clamp + sigmoid -----------------
__global__ void decode_k(
    const float* __restrict__ cls0, const float* __restrict__ reg0,
    const float* __restrict__ cls1, const float* __restrict__ reg1,
    float* __restrict__ box0, float* __restrict__ sc0,
    float* __restrict__ box1, float* __restrict__ sc1)
{
  int id = blockIdx.x * 256 + threadIdx.x;
  if (id >= 4 * 3840) return;
  int b = id / 3840, m = id - b * 3840;
  int lvl = (m >= 3072) ? 1 : 0;
  int n = lvl ? (m - 3072) : m;
  int Wd = lvl ? 16 : 32;
  float S = lvl ? 16.f : 8.f;
  double scale = lvl ? 16384.0 : 4096.0;
  int pin = n / 3, a = n - pin * 3;
  int y = pin / Wd, x = pin - y * Wd;
  double ratio = (a == 0) ? 0.5 : (a == 1 ? 1.0 : 2.0);
  float w_a = (float)sqrt(scale / ratio);
  float h_a = (float)sqrt(scale * ratio);
  float cx = ((float)x + 0.5f) * S;
  float cy = ((float)y + 0.5f) * S;
  float x1 = cx - 0.5f * w_a, y1 = cy - 0.5f * h_a;
  float x2 = cx + 0.5f * w_a, y2 = cy + 0.5f * h_a;
  x1 = fminf(fmaxf(x1, 0.f), 256.f); y1 = fminf(fmaxf(y1, 0.f), 256.f);
  x2 = fminf(fmaxf(x2, 0.f), 256.f); y2 = fminf(fmaxf(y2, 0.f), 256.f);
  float wa = x2 - x1, ha = y2 - y1;
  float cxa = x1 + 0.5f * wa, cya = y1 + 0.5f * ha;
  const float* rg = lvl ? &reg1[((size_t)b * 768 + n) * 4] : &reg0[((size_t)b * 3072 + n) * 4];
  float dx = rg[0], dy = rg[1], dw = rg[2], dh = rg[3];
  float ncx = dx * wa + cxa;
  float ncy = dy * ha + cya;
  float nw = expf(dw) * wa;
  float nh = expf(dh) * ha;
  float bx1 = ncx - 0.5f * nw, by1 = ncy - 0.5f * nh;
  float bx2 = ncx + 0.5f * nw, by2 = ncy + 0.5f * nh;
  bx1 = fminf(fmaxf(bx1, 0.f), 256.f); by1 = fminf(fmaxf(by1, 0.f), 256.f);
  bx2 = fminf(fmaxf(bx2, 0.f), 256.f); by2 = fminf(fmaxf(by2, 0.f), 256.f);
  float c = lvl ? cls1[b * 768 + n] : cls0[b * 3072 + n];
  float s = 1.f / (1.f + expf(-c));
  float* bo = lvl ? &box1[((size_t)b * 768 + n) * 4] : &box0[((size_t)b * 3072 + n) * 4];
  bo[0] = bx1; bo[1] = by1; bo[2] = bx2; bo[3] = by2;
  if (lvl) sc1[b * 768 + n] = s; else sc0[b * 3072 + n] = s;
}

// ---------------- stable descending enumeration sort per (batch,level) ------
__global__ __launch_bounds__(256) void sort_level_k(
    const float* __restrict__ sc, const float* __restrict__ box,
    float* __restrict__ ssc, float* __restrict__ sbox, int N, int nblk)
{
  __shared__ float s[3072];
  int b = blockIdx.x / nblk;
  int c = blockIdx.x - b * nblk;
  const float* scb = sc + (size_t)b * N;
  for (int j = threadIdx.x; j < N; j += 256) s[j] = scb[j];
  __syncthreads();
  int i = c * 256 + threadIdx.x;
  float si = s[i];
  int rank = 0;
  for (int j = 0; j < N; ++j) {
    float sj = s[j];
    rank += (sj > si) || (sj == si && j < i);
  }
  ssc[(size_t)b * N + rank] = si;
  float4 bi = ((const float4*)box)[(size_t)b * N + i];
  ((float4*)sbox)[(size_t)b * N + rank] = bi;
}

// ---------------- NMS suppression bitmask (row-major), LDS-staged tile ------
__global__ __launch_bounds__(256) void nms_mask_k(
    const float* __restrict__ sbox, unsigned long long* __restrict__ mask,
    int N, int words)
{
  __shared__ float4 bj[64];
  int w = blockIdx.x;
  int i = blockIdx.y * 256 + threadIdx.x;
  int b = blockIdx.z;
  if (threadIdx.x < 64)
    bj[threadIdx.x] = ((const float4*)sbox)[(size_t)b * N + w * 64 + threadIdx.x];
  __syncthreads();
  float4 bi = ((const float4*)sbox)[(size_t)b * N + i];
  float ai = (bi.z - bi.x) * (bi.w - bi.y);
  unsigned long long m = 0ull;
#pragma unroll 16
  for (int jj = 0; jj < 64; ++jj) {
    int j = w * 64 + jj;
    float4 bv = bj[jj];
    float lx = fmaxf(bi.x, bv.x), ly = fmaxf(bi.y, bv.y);
    float rx = fminf(bi.z, bv.z), ry = fminf(bi.w, bv.w);
    float iw = fmaxf(rx - lx, 0.f), ih = fmaxf(ry - ly, 0.f);
    float inter = iw * ih;
    float aj = (bv.z - bv.x) * (bv.w - bv.y);
    float iou = inter / (ai + aj - inter);   // NaN compares false, matches jnp
    if ((iou > 0.7f) & (j > i)) m |= (1ull << jj);
  }
  mask[((size_t)b * N + i) * words + w] = m;
}

// ---------------- transposed diagonal tiles ---------------------------------
__global__ __launch_bounds__(64) void col_diag_k(
    const float* __restrict__ sbox, unsigned long long* __restrict__ colD, int N)
{
  __shared__ float4 tb[64];
  int t = blockIdx.x, b = blockIdx.y;
  int lane = threadIdx.x;
  tb[lane] = ((const float4*)sbox)[(size_t)b * N + t * 64 + lane];
  __syncthreads();
  float4 bq = tb[lane];
  float aq = (bq.z - bq.x) * (bq.w - bq.y);
  unsigned long long col = 0ull;
#pragma unroll 16
  for (int ii = 0; ii < 64; ++ii) {
    float4 bi = tb[ii];
    float lx = fmaxf(bq.x, bi.x), ly = fmaxf(bq.y, bi.y);
    float rx = fminf(bq.z, bi.z), ry = fminf(bq.w, bi.w);
    float iw = fmaxf(rx - lx, 0.f), ih = fmaxf(ry - ly, 0.f);
    float inter = iw * ih;
    float ai = (bi.z - bi.x) * (bi.w - bi.y);
    float iou = inter / (aq + ai - inter);
    if ((iou > 0.7f) & (lane > ii)) col |= (1ull << ii);
  }
  colD[(size_t)b * N + t * 64 + lane] = col;
}

// ---------------- exact greedy scan: ballot-based, one wave per (b,lvl) -----
__global__ __launch_bounds__(64) void nms_scan_k(
    const float* __restrict__ ssc0, const float* __restrict__ sbox0,
    const unsigned long long* __restrict__ mask0,
    const unsigned long long* __restrict__ colD0,
    const float* __restrict__ ssc1, const float* __restrict__ sbox1,
    const unsigned long long* __restrict__ mask1,
    const unsigned long long* __restrict__ colD1,
    float* __restrict__ cb, float* __restrict__ cs)
{
  int z = blockIdx.x;
  int lvl = z >> 2, b = z & 3;
  int N = lvl ? 768 : 3072;
  int words = lvl ? 12 : 48;
  const float* ssc = lvl ? ssc1 : ssc0;
  const float* sbox = lvl ? sbox1 : sbox0;
  const unsigned long long* mask = (lvl ? mask1 : mask0) + (size_t)b * N * words;
  const unsigned long long* colD = (lvl ? colD1 : colD0) + (size_t)b * N;
  const int lane = threadIdx.x;
  float* cbb = cb + ((size_t)b * 2000 + lvl * 1000) * 4;
  float* csb = cs + (size_t)b * 2000 + lvl * 1000;
  for (int q = lane; q < 1000; q += 64) {
    csb[q] = -1.f;
    ((float4*)cbb)[q] = make_float4(-1.f, -1.f, -1.f, -1.f);
  }
  unsigned long long removed = 0ull;   // lane w (< words) holds removed word w
  int kept_base = 0;
  for (int t = 0; t < words; ++t) {
    unsigned long long wr = __shfl(removed, t);
    unsigned long long col = colD[t * 64 + lane];
    bool sup = (wr >> lane) & 1ull;
#pragma unroll
    for (int i = 0; i < 64; ++i) {                  // pure VALU/ballot chain
      unsigned long long supv = __ballot(sup);
      bool keep_i = !((supv >> i) & 1ull);
      sup = sup | (keep_i & ((col >> i) & 1ull));
    }
    unsigned long long keep64 = ~__ballot(sup);
    if (!sup) {
      int rank = kept_base + __popcll(keep64 & ((1ull << lane) - 1ull));
      if (rank < 1000) {
        int i = t * 64 + lane;
        csb[rank] = ssc[(size_t)b * N + i];
        ((float4*)cbb)[rank] = ((const float4*)sbox)[(size_t)b * N + i];
      }
    }
    if (lane > t && lane < words) {                 // propagate suppression
      const unsigned long long* row = mask + (size_t)t * 64 * words + lane;
      unsigned long long acc = removed;
#pragma unroll 16
      for (int bb = 0; bb < 64; ++bb) {
        unsigned long long m = row[(size_t)bb * words];
        acc |= (((keep64 >> bb) & 1ull) ? m : 0ull);
      }
      removed = acc;
    }
    kept_base += __popcll(keep64);
  }
}

// ---------------- final stable descending sort of 2000, gather boxes --------
__global__ __launch_bounds__(256) void final_sort_k(
    const float* __restrict__ cs, const float* __restrict__ cb,
    float* __restrict__ out)
{
  __shared__ float s[2000];
  int b = blockIdx.x >> 3, c = blockIdx.x & 7;
  const float* csb = cs + (size_t)b * 2000;
  for (int j = threadIdx.x; j < 2000; j += 256) s[j] = csb[j];
  __syncthreads();
  if (threadIdx.x >= 250) return;
  int li = c * 250 + threadIdx.x;
  float si = s[li];
  int rank = 0;
  for (int j = 0; j < 2000; ++j) {
    float sj = s[j];
    rank += (sj > si) || (sj == si && j < li);
  }
  float4 bi = ((const float4*)cb)[(size_t)b * 2000 + li];
  ((float4*)out)[(size_t)b * 2000 + rank] = bi;
}

// ============================================================================
extern "C" void kernel_launch(void* const* d_in, const int* in_sizes, int n_in,
                              void* d_out, int out_size, void* d_ws, size_t ws_size,
                              hipStream_t stream) {
  const float* feat0  = (const float*)d_in[0];
  const float* feat1  = (const float*)d_in[1];
  const float* conv_w = (const float*)d_in[2];
  const float* conv_b = (const float*)d_in[3];
  const float* cls_w  = (const float*)d_in[4];
  const float* cls_b  = (const float*)d_in[5];
  const float* reg_w  = (const float*)d_in[6];
  const float* reg_b  = (const float*)d_in[7];

  char* p = (char*)d_ws;
  auto alloc = [&](size_t bytes) {
    char* r = p;
    p += (bytes + 255) & ~(size_t)255;
    return r;
  };
  float* w_t  = (float*)alloc((size_t)2304 * 256 * 4);
  float* x0t  = (float*)alloc((size_t)4096 * 256 * 4);
  float* x1t  = (float*)alloc((size_t)1024 * 256 * 4);
  double* part0 = (double*)alloc((size_t)4 * 4096 * 256 * 8);   // 33.6 MB
  double* part1 = (double*)alloc((size_t)8 * 1024 * 256 * 8);   // 16.8 MB
  float* cls0 = (float*)alloc((size_t)4 * 3072 * 4);
  float* reg0 = (float*)alloc((size_t)4 * 3072 * 16);
  float* cls1 = (float*)alloc((size_t)4 * 768 * 4);
  float* reg1 = (float*)alloc((size_t)4 * 768 * 16);
  float* box0 = (float*)alloc((size_t)4 * 3072 * 16);
  float* sc0  = (float*)alloc((size_t)4 * 3072 * 4);
  float* box1 = (float*)alloc((size_t)4 * 768 * 16);
  float* sc1  = (float*)alloc((size_t)4 * 768 * 4);
  float* sbox0 = (float*)alloc((size_t)4 * 3072 * 16);
  float* ssc0  = (float*)alloc((size_t)4 * 3072 * 4);
  float* sbox1 = (float*)alloc((size_t)4 * 768 * 16);
  float* ssc1  = (float*)alloc((size_t)4 * 768 * 4);
  unsigned long long* mask0 = (unsigned long long*)alloc((size_t)4 * 3072 * 48 * 8);
  unsigned long long* mask1 = (unsigned long long*)alloc((size_t)4 * 768 * 12 * 8);
  unsigned long long* colD0 = (unsigned long long*)alloc((size_t)4 * 3072 * 8);
  unsigned long long* colD1 = (unsigned long long*)alloc((size_t)4 * 768 * 8);
  float* cb = (float*)alloc((size_t)4 * 2000 * 16);
  float* cs = (float*)alloc((size_t)4 * 2000 * 4);

  transpose_w_k<<<(2304 * 256 + 255) / 256, 256, 0, stream>>>(conv_w, w_t);
  conv3_sk_u<<<1536, 256, 0, stream>>>(feat0, feat1, w_t, part0, part1);
  reduce_relu_k<4><<<(4096 * 256 + 255) / 256, 256, 0, stream>>>(part0, conv_b, x0t, 4096);
  reduce_relu_k<8><<<(1024 * 256 + 255) / 256, 256, 0, stream>>>(part1, conv_b, x1t, 1024);
  heads_k<<<320, 256, 0, stream>>>(x0t, x1t, cls_w, cls_b, reg_w, reg_b,
                                   cls0, reg0, cls1, reg1);
  decode_k<<<(4 * 3840 + 255) / 256, 256, 0, stream>>>(cls0, reg0, cls1, reg1,
                                                       box0, sc0, box1, sc1);
  sort_level_k<<<4 * 12, 256, 0, stream>>>(sc0, box0, ssc0, sbox0, 3072, 12);
  sort_level_k<<<4 * 3, 256, 0, stream>>>(sc1, box1, ssc1, sbox1, 768, 3);
  nms_mask_k<<<dim3(48, 12, 4), 256, 0, stream>>>(sbox0, mask0, 3072, 48);
  nms_mask_k<<<dim3(12, 3, 4), 256, 0, stream>>>(sbox1, mask1, 768, 12);
  col_diag_k<<<dim3(48, 4), 64, 0, stream>>>(sbox0, colD0, 3072);
  col_diag_k<<<dim3(12, 4), 64, 0, stream>>>(sbox1, colD1, 768);
  nms_scan_k<<<8, 64, 0, stream>>>(ssc0, sbox0, mask0, colD0,
                                   ssc1, sbox1, mask1, colD1, cb, cs);
  final_sort_k<<<32, 256, 0, stream>>>(cs, cb, (float*)d_out);
}

// Round 5
// 618.844 us; speedup vs baseline: 2.6230x; 1.0977x over previous
//
#include <hip/hip_runtime.h>
#include <math.h>

// ============================================================================
// RPN pipeline for MI355X.
// L0: H=W=32, stride 8, scale 4096 ; L1: H=W=16, stride 16, scale 16384
// A=3 ratios {0.5,1,2}. N0=3072, N1=768 anchors/batch. BS=4.
// Numeric recipe (validated bitwise R1-R4, absmax 0.0): fp64 accumulation for
// every sum feeding the score/box path, fp32 rounding at layer boundaries,
// fp32 expf/sigmoid. fp64 regrouping is free (1e-16 vs fp32 ulp margin).
// R5: (a) conv register-prefetch pipeline + balanced 1280-block grid (5/CU,
// equal 36 ktiles); (b) launch fusion 14 -> 7 (reduce+heads+decode -> rhd_k
// with fp64 butterfly dot; col_diag folded into mask kernel; both sort levels
// one launch); (c) w_t pre-converted to fp64.
// ============================================================================

// ---------------- transpose conv_w [256][2304] -> fp64 w_t [2304][256] ------
__global__ void transpose_w_k(const float* __restrict__ w, double* __restrict__ wt) {
  int idx = blockIdx.x * 256 + threadIdx.x;
  if (idx >= 2304 * 256) return;
  int k = idx >> 8, oc = idx & 255;
  wt[idx] = (double)w[oc * 2304 + k];
}

// ---------------- merged conv3x3 implicit GEMM, split-K, reg-prefetch -------
// 1280 blocks, all 36 ktiles: bid<1024: L0 (kc=bid>>8, oc=bid&3, p=(bid>>2)&63)
//                             else L1: b2=bid-1024 (kc=b2>>6, oc=b2&3, p=(b2>>2)&15)
__global__ __launch_bounds__(256) void conv3_sk_u(
    const float* __restrict__ feat0, const float* __restrict__ feat1,
    const double* __restrict__ wt,
    double* __restrict__ part0, double* __restrict__ part1)
{
  __shared__ double Ald[16][64];
  __shared__ double Bld[16][64];
  const int t = threadIdx.x;
  const int tx = t & 15, ty = t >> 4;
  const int bid = blockIdx.x;
  const float* feat;
  double* part;
  int oc_t, p_t, k_base, hw_sh, w_sh, H;
  if (bid < 1024) {
    int kc = bid >> 8;
    feat = feat0; part = part0 + (size_t)kc * 4096 * 256;
    oc_t = bid & 3; p_t = (bid >> 2) & 63;
    k_base = kc * 576; hw_sh = 10; w_sh = 5; H = 32;
  } else {
    int b2 = bid - 1024;
    int kc = b2 >> 6;
    feat = feat1; part = part1 + (size_t)kc * 1024 * 256;
    oc_t = b2 & 3; p_t = (b2 >> 2) & 15;
    k_base = kc * 576; hw_sh = 8; w_sh = 4; H = 16;
  }
  const int oc_base = oc_t * 64;
  const int p_base  = p_t * 64;
  const int wmask = H - 1, hwmask = (1 << hw_sh) - 1;

  double a_r[4];
  float  b_r[4];
  // prefetch lambda: load ktile kt into regs
  auto load_tile = [&](int kt) {
    const int k0 = k_base + kt * 16;
#pragma unroll
    for (int r = 0; r < 4; ++r) {
      int e = t + r * 256;
      int kk = e >> 6, ocl = e & 63;
      a_r[r] = wt[(k0 + kk) * 256 + oc_base + ocl];
    }
#pragma unroll
    for (int r = 0; r < 4; ++r) {
      int e = t + r * 256;
      int kk = e >> 6, pxl = e & 63;
      int p = p_base + pxl;
      int b = p >> hw_sh, pin = p & hwmask;
      int y = pin >> w_sh, x = pin & wmask;
      int k = k0 + kk;
      int ic = k / 9, rr = k - ic * 9;
      int ky = rr / 3, kx = rr - ky * 3;
      int iy = y + ky - 1, ix = x + kx - 1;
      float v = 0.f;
      if ((unsigned)iy < (unsigned)H && (unsigned)ix < (unsigned)H)
        v = feat[(((b << 8) + ic) << hw_sh) + (iy << w_sh) + ix];
      b_r[r] = v;
    }
  };

  double acc[4][4] = {};
  load_tile(0);
  for (int kt = 0; kt < 36; ++kt) {
#pragma unroll
    for (int r = 0; r < 4; ++r) {                 // regs -> LDS
      int e = t + r * 256;
      Ald[e >> 6][e & 63] = a_r[r];
    }
#pragma unroll
    for (int r = 0; r < 4; ++r) {
      int e = t + r * 256;
      Bld[e >> 6][e & 63] = (double)b_r[r];
    }
    __syncthreads();
    if (kt + 1 < 36) load_tile(kt + 1);           // global loads overlap compute
#pragma unroll
    for (int kk = 0; kk < 16; ++kk) {
      double a[4], bb[4];
#pragma unroll
      for (int i = 0; i < 4; ++i) a[i] = Ald[kk][ty + 16 * i];
#pragma unroll
      for (int j = 0; j < 4; ++j) bb[j] = Bld[kk][tx + 16 * j];
#pragma unroll
      for (int i = 0; i < 4; ++i)
#pragma unroll
        for (int j = 0; j < 4; ++j) acc[i][j] += a[i] * bb[j];
    }
    __syncthreads();
  }
#pragma unroll
  for (int i = 0; i < 4; ++i) {
    int oc = oc_base + ty + 16 * i;
#pragma unroll
    for (int j = 0; j < 4; ++j) {
      int p = p_base + tx + 16 * j;
      part[(size_t)p * 256 + oc] = acc[i][j];
    }
  }
}

// ---------------- fused reduce(KS=4)+bias+ReLU + 1x1 heads + decode ---------
// one wave per position p (5120 total); lanes hold 4 channels each.
__global__ __launch_bounds__(256) void rhd_k(
    const double* __restrict__ part0, const double* __restrict__ part1,
    const float* __restrict__ conv_b,
    const float* __restrict__ cls_w, const float* __restrict__ cls_b,
    const float* __restrict__ reg_w, const float* __restrict__ reg_b,
    float* __restrict__ box0, float* __restrict__ sc0,
    float* __restrict__ box1, float* __restrict__ sc1)
{
  int wid = (blockIdx.x * 256 + threadIdx.x) >> 6;
  int lane = threadIdx.x & 63;
  int lvl = wid >= 4096;
  const double* part = lvl ? part1 : part0;
  int p = lvl ? wid - 4096 : wid;
  int M = lvl ? 1024 : 4096;
  // x[c] = relu(float(bias_c + sum_ks part[ks][p][c])), c = lane + 64q
  float xv[4];
#pragma unroll
  for (int q = 0; q < 4; ++q) {
    int c = lane + 64 * q;
    double s = (double)conv_b[c];
#pragma unroll
    for (int ks = 0; ks < 4; ++ks)
      s += part[(size_t)ks * M * 256 + (size_t)p * 256 + c];
    float f = (float)s;
    xv[q] = f > 0.f ? f : 0.f;
  }
  // 15 fp64 dot products (3 cls + 12 reg)
  double acc[15];
#pragma unroll
  for (int o = 0; o < 15; ++o) {
    const float* wr = (o < 3) ? (cls_w + o * 256) : (reg_w + (o - 3) * 256);
    double a = 0.0;
#pragma unroll
    for (int q = 0; q < 4; ++q)
      a += (double)wr[lane + 64 * q] * (double)xv[q];
    acc[o] = a;
  }
  // butterfly reduce across 64 lanes (deterministic pairwise tree)
#pragma unroll
  for (int d = 1; d < 64; d <<= 1)
#pragma unroll
    for (int o = 0; o < 15; ++o)
      acc[o] += __shfl_xor(acc[o], d, 64);
  // decode: lanes 0..2 handle anchors 0..2
  if (lane < 3) {
    int a = lane;
    float cls = (float)(acc[a] + (double)cls_b[a]);
    float score = 1.f / (1.f + expf(-cls));
    float dx = (float)(acc[3 + a * 4 + 0] + (double)reg_b[a * 4 + 0]);
    float dy = (float)(acc[3 + a * 4 + 1] + (double)reg_b[a * 4 + 1]);
    float dw = (float)(acc[3 + a * 4 + 2] + (double)reg_b[a * 4 + 2]);
    float dh = (float)(acc[3 + a * 4 + 3] + (double)reg_b[a * 4 + 3]);
    int hw_sh = lvl ? 8 : 10, w_sh = lvl ? 4 : 5, Wd = lvl ? 16 : 32;
    float S = lvl ? 16.f : 8.f;
    double scale = lvl ? 16384.0 : 4096.0;
    int b = p >> hw_sh, pin = p & ((1 << hw_sh) - 1);
    int y = pin >> w_sh, x = pin & (Wd - 1);
    double ratio = (a == 0) ? 0.5 : (a == 1 ? 1.0 : 2.0);
    float w_a = (float)sqrt(scale / ratio);
    float h_a = (float)sqrt(scale * ratio);
    float cx = ((float)x + 0.5f) * S;
    float cy = ((float)y + 0.5f) * S;
    float x1 = cx - 0.5f * w_a, y1 = cy - 0.5f * h_a;
    float x2 = cx + 0.5f * w_a, y2 = cy + 0.5f * h_a;
    x1 = fminf(fmaxf(x1, 0.f), 256.f); y1 = fminf(fmaxf(y1, 0.f), 256.f);
    x2 = fminf(fmaxf(x2, 0.f), 256.f); y2 = fminf(fmaxf(y2, 0.f), 256.f);
    float wa = x2 - x1, ha = y2 - y1;
    float cxa = x1 + 0.5f * wa, cya = y1 + 0.5f * ha;
    float ncx = dx * wa + cxa;
    float ncy = dy * ha + cya;
    float nw = expf(dw) * wa;
    float nh = expf(dh) * ha;
    float bx1 = ncx - 0.5f * nw, by1 = ncy - 0.5f * nh;
    float bx2 = ncx + 0.5f * nw, by2 = ncy + 0.5f * nh;
    bx1 = fminf(fmaxf(bx1, 0.f), 256.f); by1 = fminf(fmaxf(by1, 0.f), 256.f);
    bx2 = fminf(fmaxf(bx2, 0.f), 256.f); by2 = fminf(fmaxf(by2, 0.f), 256.f);
    int n = pin * 3 + a;
    if (lvl) {
      ((float4*)box1)[(size_t)b * 768 + n] = make_float4(bx1, by1, bx2, by2);
      sc1[b * 768 + n] = score;
    } else {
      ((float4*)box0)[(size_t)b * 3072 + n] = make_float4(bx1, by1, bx2, by2);
      sc0[b * 3072 + n] = score;
    }
  }
}

// ---------------- stable descending enumeration sort, both levels -----------
__global__ __launch_bounds__(256) void sort_level_k(
    const float* __restrict__ sc0, const float* __restrict__ box0,
    float* __restrict__ ssc0, float* __restrict__ sbox0,
    const float* __restrict__ sc1, const float* __restrict__ box1,
    float* __restrict__ ssc1, float* __restrict__ sbox1)
{
  __shared__ float s[3072];
  int z = blockIdx.x;
  const float *sc, *box; float *ssc, *sbox; int N, b, c;
  if (z < 48) { sc = sc0; box = box0; ssc = ssc0; sbox = sbox0; N = 3072; b = z / 12; c = z % 12; }
  else { int z2 = z - 48; sc = sc1; box = box1; ssc = ssc1; sbox = sbox1; N = 768; b = z2 / 3; c = z2 % 3; }
  const float* scb = sc + (size_t)b * N;
  for (int j = threadIdx.x; j < N; j += 256) s[j] = scb[j];
  __syncthreads();
  int i = c * 256 + threadIdx.x;
  float si = s[i];
  int rank = 0;
  for (int j = 0; j < N; ++j) {
    float sj = s[j];
    rank += (sj > si) || (sj == si && j < i);
  }
  ssc[(size_t)b * N + rank] = si;
  float4 bi = ((const float4*)box)[(size_t)b * N + i];
  ((float4*)sbox)[(size_t)b * N + rank] = bi;
}

// ---------------- NMS bitmask + transposed diagonal tiles, one kernel -------
// bids [0,2304): L0 mask; [2304,2448): L1 mask; [2448,2496): L0 col (4 units
// per block); [2496,2508): L1 col.
__global__ __launch_bounds__(256) void mask_col_k(
    const float* __restrict__ sbox0, const float* __restrict__ sbox1,
    unsigned long long* __restrict__ mask0, unsigned long long* __restrict__ mask1,
    unsigned long long* __restrict__ colD0, unsigned long long* __restrict__ colD1)
{
  int bid = blockIdx.x;
  if (bid < 2448) {
    __shared__ float4 bj[64];
    const float* sbox; unsigned long long* mask; int N, words, w, i_ch, b;
    if (bid < 2304) {
      sbox = sbox0; mask = mask0; N = 3072; words = 48;
      w = bid % 48; int r = bid / 48; i_ch = r % 12; b = r / 12;
    } else {
      int z = bid - 2304;
      sbox = sbox1; mask = mask1; N = 768; words = 12;
      w = z % 12; int r = z / 12; i_ch = r % 3; b = r / 3;
    }
    int i = i_ch * 256 + threadIdx.x;
    if (threadIdx.x < 64)
      bj[threadIdx.x] = ((const float4*)sbox)[(size_t)b * N + w * 64 + threadIdx.x];
    __syncthreads();
    float4 bi = ((const float4*)sbox)[(size_t)b * N + i];
    float ai = (bi.z - bi.x) * (bi.w - bi.y);
    unsigned long long m = 0ull;
#pragma unroll 16
    for (int jj = 0; jj < 64; ++jj) {
      int j = w * 64 + jj;
      float4 bv = bj[jj];
      float lx = fmaxf(bi.x, bv.x), ly = fmaxf(bi.y, bv.y);
      float rx = fminf(bi.z, bv.z), ry = fminf(bi.w, bv.w);
      float iw = fmaxf(rx - lx, 0.f), ih = fmaxf(ry - ly, 0.f);
      float inter = iw * ih;
      float aj = (bv.z - bv.x) * (bv.w - bv.y);
      float iou = inter / (ai + aj - inter);   // NaN compares false, matches jnp
      if ((iou > 0.7f) & (j > i)) m |= (1ull << jj);
    }
    mask[((size_t)b * N + i) * words + w] = m;
  } else {
    __shared__ float4 tb[4][64];
    int sub = threadIdx.x >> 6, lane = threadIdx.x & 63;
    const float* sbox; unsigned long long* colD; int N, tile, b;
    if (bid < 2496) {
      int unit = (bid - 2448) * 4 + sub;
      sbox = sbox0; colD = colD0; N = 3072;
      tile = unit % 48; b = unit / 48;
    } else {
      int unit = (bid - 2496) * 4 + sub;
      sbox = sbox1; colD = colD1; N = 768;
      tile = unit % 12; b = unit / 12;
    }
    tb[sub][lane] = ((const float4*)sbox)[(size_t)b * N + tile * 64 + lane];
    __syncthreads();
    float4 bq = tb[sub][lane];
    float aq = (bq.z - bq.x) * (bq.w - bq.y);
    unsigned long long col = 0ull;
#pragma unroll 16
    for (int ii = 0; ii < 64; ++ii) {
      float4 bi = tb[sub][ii];
      float lx = fmaxf(bq.x, bi.x), ly = fmaxf(bq.y, bi.y);
      float rx = fminf(bq.z, bi.z), ry = fminf(bq.w, bi.w);
      float iw = fmaxf(rx - lx, 0.f), ih = fmaxf(ry - ly, 0.f);
      float inter = iw * ih;
      float ai = (bi.z - bi.x) * (bi.w - bi.y);
      float iou = inter / (aq + ai - inter);
      if ((iou > 0.7f) & (lane > ii)) col |= (1ull << ii);
    }
    colD[(size_t)b * N + tile * 64 + lane] = col;
  }
}

// ---------------- exact greedy scan: ballot-based, one wave per (b,lvl) -----
__global__ __launch_bounds__(64) void nms_scan_k(
    const float* __restrict__ ssc0, const float* __restrict__ sbox0,
    const unsigned long long* __restrict__ mask0,
    const unsigned long long* __restrict__ colD0,
    const float* __restrict__ ssc1, const float* __restrict__ sbox1,
    const unsigned long long* __restrict__ mask1,
    const unsigned long long* __restrict__ colD1,
    float* __restrict__ cb, float* __restrict__ cs)
{
  int z = blockIdx.x;
  int lvl = z >> 2, b = z & 3;
  int N = lvl ? 768 : 3072;
  int words = lvl ? 12 : 48;
  const float* ssc = lvl ? ssc1 : ssc0;
  const float* sbox = lvl ? sbox1 : sbox0;
  const unsigned long long* mask = (lvl ? mask1 : mask0) + (size_t)b * N * words;
  const unsigned long long* colD = (lvl ? colD1 : colD0) + (size_t)b * N;
  const int lane = threadIdx.x;
  float* cbb = cb + ((size_t)b * 2000 + lvl * 1000) * 4;
  float* csb = cs + (size_t)b * 2000 + lvl * 1000;
  for (int q = lane; q < 1000; q += 64) {
    csb[q] = -1.f;
    ((float4*)cbb)[q] = make_float4(-1.f, -1.f, -1.f, -1.f);
  }
  unsigned long long removed = 0ull;   // lane w (< words) holds removed word w
  int kept_base = 0;
  for (int t = 0; t < words; ++t) {
    unsigned long long wr = __shfl(removed, t);
    unsigned long long col = colD[t * 64 + lane];
    bool sup = (wr >> lane) & 1ull;
#pragma unroll
    for (int i = 0; i < 64; ++i) {                // pure VALU/ballot chain
      unsigned long long supv = __ballot(sup);
      bool keep_i = !((supv >> i) & 1ull);
      sup = sup | (keep_i & ((col >> i) & 1ull));
    }
    unsigned long long keep64 = ~__ballot(sup);
    if (!sup) {
      int rank = kept_base + __popcll(keep64 & ((1ull << lane) - 1ull));
      if (rank < 1000) {
        int i = t * 64 + lane;
        csb[rank] = ssc[(size_t)b * N + i];
        ((float4*)cbb)[rank] = ((const float4*)sbox)[(size_t)b * N + i];
      }
    }
    if (lane > t && lane < words) {               // propagate suppression
      const unsigned long long* row = mask + (size_t)t * 64 * words + lane;
      unsigned long long acc = removed;
#pragma unroll 16
      for (int bb = 0; bb < 64; ++bb) {
        unsigned long long m = row[(size_t)bb * words];
        acc |= (((keep64 >> bb) & 1ull) ? m : 0ull);
      }
      removed = acc;
    }
    kept_base += __popcll(keep64);
  }
}

// ---------------- final stable descending sort of 2000, gather boxes --------
__global__ __launch_bounds__(256) void final_sort_k(
    const float* __restrict__ cs, const float* __restrict__ cb,
    float* __restrict__ out)
{
  __shared__ float s[2000];
  int b = blockIdx.x >> 3, c = blockIdx.x & 7;
  const float* csb = cs + (size_t)b * 2000;
  for (int j = threadIdx.x; j < 2000; j += 256) s[j] = csb[j];
  __syncthreads();
  if (threadIdx.x >= 250) return;
  int li = c * 250 + threadIdx.x;
  float si = s[li];
  int rank = 0;
  for (int j = 0; j < 2000; ++j) {
    float sj = s[j];
    rank += (sj > si) || (sj == si && j < li);
  }
  float4 bi = ((const float4*)cb)[(size_t)b * 2000 + li];
  ((float4*)out)[(size_t)b * 2000 + rank] = bi;
}

// ============================================================================
extern "C" void kernel_launch(void* const* d_in, const int* in_sizes, int n_in,
                              void* d_out, int out_size, void* d_ws, size_t ws_size,
                              hipStream_t stream) {
  const float* feat0  = (const float*)d_in[0];
  const float* feat1  = (const float*)d_in[1];
  const float* conv_w = (const float*)d_in[2];
  const float* conv_b = (const float*)d_in[3];
  const float* cls_w  = (const float*)d_in[4];
  const float* cls_b  = (const float*)d_in[5];
  const float* reg_w  = (const float*)d_in[6];
  const float* reg_b  = (const float*)d_in[7];

  char* p = (char*)d_ws;
  auto alloc = [&](size_t bytes) {
    char* r = p;
    p += (bytes + 255) & ~(size_t)255;
    return r;
  };
  double* w_t   = (double*)alloc((size_t)2304 * 256 * 8);        //  4.7 MB
  double* part0 = (double*)alloc((size_t)4 * 4096 * 256 * 8);    // 33.6 MB
  double* part1 = (double*)alloc((size_t)4 * 1024 * 256 * 8);    //  8.4 MB
  float* box0 = (float*)alloc((size_t)4 * 3072 * 16);
  float* sc0  = (float*)alloc((size_t)4 * 3072 * 4);
  float* box1 = (float*)alloc((size_t)4 * 768 * 16);
  float* sc1  = (float*)alloc((size_t)4 * 768 * 4);
  float* sbox0 = (float*)alloc((size_t)4 * 3072 * 16);
  float* ssc0  = (float*)alloc((size_t)4 * 3072 * 4);
  float* sbox1 = (float*)alloc((size_t)4 * 768 * 16);
  float* ssc1  = (float*)alloc((size_t)4 * 768 * 4);
  unsigned long long* mask0 = (unsigned long long*)alloc((size_t)4 * 3072 * 48 * 8);
  unsigned long long* mask1 = (unsigned long long*)alloc((size_t)4 * 768 * 12 * 8);
  unsigned long long* colD0 = (unsigned long long*)alloc((size_t)4 * 3072 * 8);
  unsigned long long* colD1 = (unsigned long long*)alloc((size_t)4 * 768 * 8);
  float* cb = (float*)alloc((size_t)4 * 2000 * 16);
  float* cs = (float*)alloc((size_t)4 * 2000 * 4);

  transpose_w_k<<<(2304 * 256 + 255) / 256, 256, 0, stream>>>(conv_w, w_t);
  conv3_sk_u<<<1280, 256, 0, stream>>>(feat0, feat1, w_t, part0, part1);
  rhd_k<<<1280, 256, 0, stream>>>(part0, part1, conv_b, cls_w, cls_b,
                                  reg_w, reg_b, box0, sc0, box1, sc1);
  sort_level_k<<<60, 256, 0, stream>>>(sc0, box0, ssc0, sbox0,
                                       sc1, box1, ssc1, sbox1);
  mask_col_k<<<2508, 256, 0, stream>>>(sbox0, sbox1, mask0, mask1, colD0, colD1);
  nms_scan_k<<<8, 64, 0, stream>>>(ssc0, sbox0, mask0, colD0,
                                   ssc1, sbox1, mask1, colD1, cb, cs);
  final_sort_k<<<32, 256, 0, stream>>>(cs, cb, (float*)d_out);
}